// Round 5
// baseline (425.571 us; speedup 1.0000x reference)
//
#include <hip/hip_runtime.h>

#define DD 128
#define NSLICE 8
#define CK 32

// ===========================================================================
// CSR build
// ===========================================================================

__global__ __launch_bounds__(256) void k_hist(
    const int* __restrict__ node_idx,
    const int* __restrict__ edge_idx,
    int* __restrict__ countE,
    int* __restrict__ countV,
    int nnz)
{
    int i = blockIdx.x * blockDim.x + threadIdx.x;
    if (i >= nnz) return;
    int e = __builtin_nontemporal_load(edge_idx + i);
    int n = __builtin_nontemporal_load(node_idx + i);
    atomicAdd(&countE[e], 1);
    atomicAdd(&countV[n], 1);
}

__global__ __launch_bounds__(256) void k_chunk_sums(
    const int* __restrict__ cnt, int L, int* __restrict__ partials)
{
    __shared__ int red[256];
    const int tid = threadIdx.x;
    const int base = blockIdx.x * 4096;
    int s = 0;
    for (int j = tid; j < 4096; j += 256) {
        int i = base + j;
        s += (i < L) ? cnt[i] : 0;
    }
    red[tid] = s;
    __syncthreads();
    for (int off = 128; off > 0; off >>= 1) {
        if (tid < off) red[tid] += red[tid + off];
        __syncthreads();
    }
    if (tid == 0) partials[blockIdx.x] = red[0];
}

__global__ void k_scan_partials2(int* __restrict__ pE, int nbE, int* __restrict__ totE,
                                 int* __restrict__ pV, int nbV, int* __restrict__ totV)
{
    if (threadIdx.x != 0) return;
    int* p = (blockIdx.x == 0) ? pE : pV;
    int  nb = (blockIdx.x == 0) ? nbE : nbV;
    int* tot = (blockIdx.x == 0) ? totE : totV;
    int run = 0;
    for (int b = 0; b < nb; ++b) {
        int t = p[b];
        p[b] = run;
        run += t;
    }
    *tot = run;
}

__global__ __launch_bounds__(256) void k_scan_chunks(
    const int* __restrict__ cnt, int L,
    const int* __restrict__ partials,
    int* __restrict__ rowptr, int* __restrict__ cursor)
{
    __shared__ int tsum[256];
    const int tid = threadIdx.x;
    const int tbase = blockIdx.x * 4096 + tid * 16;
    int loc[16];
    int s = 0;
    #pragma unroll
    for (int k = 0; k < 16; ++k) {
        int i = tbase + k;
        loc[k] = (i < L) ? cnt[i] : 0;
        s += loc[k];
    }
    tsum[tid] = s;
    __syncthreads();
    if (tid == 0) {
        int run = partials[blockIdx.x];
        for (int j = 0; j < 256; ++j) {
            int t = tsum[j];
            tsum[j] = run;
            run += t;
        }
    }
    __syncthreads();
    int run = tsum[tid];
    #pragma unroll
    for (int k = 0; k < 16; ++k) {
        int i = tbase + k;
        if (i < L) { rowptr[i] = run; cursor[i] = run; }
        run += loc[k];
    }
}

// ---- XCD-sliced adjacency fill -------------------------------------------
// Slice s = blockIdx % 8 -> one XCD (round-robin dispatch). Index streams are
// non-temporal so they don't evict the slice's ~1MB of dirty adjacency lines
// from that XCD's 4MB L2 -> lines coalesce -> full-line writebacks only.
__global__ __launch_bounds__(256) void k_fill_sliced(
    const int* __restrict__ node_idx,
    const int* __restrict__ edge_idx,
    int* __restrict__ cursorE, int* __restrict__ cursorV,
    int* __restrict__ adjE, int* __restrict__ adjV,
    int nnz, int E, int N)
{
    const int s = blockIdx.x & (NSLICE - 1);
    const int g = blockIdx.x >> 3;
    const int ngroups = gridDim.x >> 3;
    const int eb = (E + NSLICE - 1) / NSLICE;
    const int nb = (N + NSLICE - 1) / NSLICE;
    const int elo = s * eb, ehi = min(E, elo + eb);
    const int nlo = s * nb, nhi = min(N, nlo + nb);

    const int stride = ngroups * 256;
    for (int i = g * 256 + threadIdx.x; i < nnz; i += stride) {
        int n = __builtin_nontemporal_load(node_idx + i);
        int e = __builtin_nontemporal_load(edge_idx + i);
        if (e >= elo && e < ehi) {
            int p = atomicAdd(&cursorE[e], 1);
            adjE[p] = n;
        }
        if (n >= nlo && n < nhi) {
            int p = atomicAdd(&cursorV[n], 1);
            adjV[p] = e;
        }
    }
}

// ===========================================================================
// Gather stages
// ===========================================================================

// ---- stage 1: efeat_new[e] = mean over incident nodes of vfeat ------------
__global__ __launch_bounds__(256) void k_gather_edge(
    const float* __restrict__ vfeat,
    const int* __restrict__ rowptrE,
    const int* __restrict__ adjE,
    float* __restrict__ efeat,
    int n_edges)
{
    const int gid = (blockIdx.x * blockDim.x + threadIdx.x) >> 5;
    if (gid >= n_edges) return;
    const int lane = threadIdx.x & 31;
    const int beg = rowptrE[gid];
    const int len = rowptrE[gid + 1] - beg;

    const float* vb = vfeat + (size_t)lane * 4;
    float4 c0 = {0,0,0,0}, c1 = {0,0,0,0}, c2 = {0,0,0,0}, c3 = {0,0,0,0};

    int k = 0;
    for (; k + 4 <= len; k += 4) {
        int e0 = adjE[beg + k + 0];
        int e1 = adjE[beg + k + 1];
        int e2 = adjE[beg + k + 2];
        int e3 = adjE[beg + k + 3];
        float4 r0 = *(const float4*)(vb + (size_t)e0 * DD);
        float4 r1 = *(const float4*)(vb + (size_t)e1 * DD);
        float4 r2 = *(const float4*)(vb + (size_t)e2 * DD);
        float4 r3 = *(const float4*)(vb + (size_t)e3 * DD);
        c0.x += r0.x; c0.y += r0.y; c0.z += r0.z; c0.w += r0.w;
        c1.x += r1.x; c1.y += r1.y; c1.z += r1.z; c1.w += r1.w;
        c2.x += r2.x; c2.y += r2.y; c2.z += r2.z; c2.w += r2.w;
        c3.x += r3.x; c3.y += r3.y; c3.z += r3.z; c3.w += r3.w;
    }
    for (; k < len; ++k) {
        int e0 = adjE[beg + k];
        float4 r0 = *(const float4*)(vb + (size_t)e0 * DD);
        c0.x += r0.x; c0.y += r0.y; c0.z += r0.z; c0.w += r0.w;
    }
    float inv = (len > 0) ? 1.0f / (float)len : 0.0f;
    float4 o;
    o.x = (c0.x + c1.x + c2.x + c3.x) * inv;
    o.y = (c0.y + c1.y + c2.y + c3.y) * inv;
    o.z = (c0.z + c1.z + c2.z + c3.z) * inv;
    o.w = (c0.w + c1.w + c2.w + c3.w) * inv;
    *(float4*)(efeat + (size_t)gid * DD + lane * 4) = o;
}

// ---- stage 2 fused: vi[n] = (1-a)*degV[n]*sum(degE[e]*efeat[e]) + a*vfeat0[n]
__global__ __launch_bounds__(256) void k_gather_node_vi(
    const float* __restrict__ efeat,
    const float* __restrict__ degE,
    const float* __restrict__ degV,
    const float* __restrict__ vfeat0,
    const float* __restrict__ alpha,
    const int* __restrict__ rowptrV,
    const int* __restrict__ adjV,
    float* __restrict__ vi,
    int n_nodes)
{
    const int gid = (blockIdx.x * blockDim.x + threadIdx.x) >> 5;
    if (gid >= n_nodes) return;
    const int lane = threadIdx.x & 31;
    const int beg = rowptrV[gid];
    const int len = rowptrV[gid + 1] - beg;

    const float* eb = efeat + (size_t)lane * 4;
    float4 c0 = {0,0,0,0}, c1 = {0,0,0,0}, c2 = {0,0,0,0}, c3 = {0,0,0,0};

    int k = 0;
    for (; k + 4 <= len; k += 4) {
        int e0 = adjV[beg + k + 0];
        int e1 = adjV[beg + k + 1];
        int e2 = adjV[beg + k + 2];
        int e3 = adjV[beg + k + 3];
        float w0 = degE[e0], w1 = degE[e1], w2 = degE[e2], w3 = degE[e3];
        float4 r0 = *(const float4*)(eb + (size_t)e0 * DD);
        float4 r1 = *(const float4*)(eb + (size_t)e1 * DD);
        float4 r2 = *(const float4*)(eb + (size_t)e2 * DD);
        float4 r3 = *(const float4*)(eb + (size_t)e3 * DD);
        c0.x += w0 * r0.x; c0.y += w0 * r0.y; c0.z += w0 * r0.z; c0.w += w0 * r0.w;
        c1.x += w1 * r1.x; c1.y += w1 * r1.y; c1.z += w1 * r1.z; c1.w += w1 * r1.w;
        c2.x += w2 * r2.x; c2.y += w2 * r2.y; c2.z += w2 * r2.z; c2.w += w2 * r2.w;
        c3.x += w3 * r3.x; c3.y += w3 * r3.y; c3.z += w3 * r3.z; c3.w += w3 * r3.w;
    }
    for (; k < len; ++k) {
        int e0 = adjV[beg + k];
        float w0 = degE[e0];
        float4 r0 = *(const float4*)(eb + (size_t)e0 * DD);
        c0.x += w0 * r0.x; c0.y += w0 * r0.y; c0.z += w0 * r0.z; c0.w += w0 * r0.w;
    }
    const float a = alpha[0];
    const float s = (1.0f - a) * degV[gid];
    const float4 f = *(const float4*)(vfeat0 + (size_t)gid * DD + lane * 4);
    float4 o;
    o.x = s * (c0.x + c1.x + c2.x + c3.x) + a * f.x;
    o.y = s * (c0.y + c1.y + c2.y + c3.y) + a * f.y;
    o.z = s * (c0.z + c1.z + c2.z + c3.z) + a * f.z;
    o.w = s * (c0.w + c1.w + c2.w + c3.w) + a * f.w;
    *(float4*)(vi + (size_t)gid * DD + lane * 4) = o;
}

// ---------------------------------------------------------------------------
// K-chunked, double-buffered epilogue GEMM, in place on vout (vi -> v).
// LDS = 52 KB -> 3 blocks/CU.
// ---------------------------------------------------------------------------
__global__ __launch_bounds__(256) void k_gemm_vi(
    float* __restrict__ vout,           // in: vi, out: v   [N][128]
    const float* __restrict__ W,        // [128][128]
    const float* __restrict__ beta,
    int n_nodes)
{
    __shared__ float Wc[2][128][CK + 4];
    __shared__ float Ac[2][64][CK];

    const int tid = threadIdx.x;
    const float b = beta[0];
    const int nb = blockIdx.x * 64;

    const int tx = tid & 31;
    const int ty = tid >> 5;

    float acc[8][4];
    #pragma unroll
    for (int i = 0; i < 8; ++i)
        #pragma unroll
        for (int j = 0; j < 4; ++j) acc[i][j] = 0.0f;

    auto stage = [&](int chunk, int buf) {
        const int kb = chunk * CK;
        #pragma unroll
        for (int p = 0; p < 4; ++p) {
            int idx = tid + p * 256;
            int row = idx >> 3;
            int l4 = (idx & 7) << 2;
            *(float4*)&Wc[buf][row][l4] = *(const float4*)(W + row * DD + kb + l4);
        }
        #pragma unroll
        for (int p = 0; p < 2; ++p) {
            int idx = tid + p * 256;
            int row = idx >> 3;
            int l4 = (idx & 7) << 2;
            int n = nb + row;
            float4 v = {0, 0, 0, 0};
            if (n < n_nodes) v = *(const float4*)(vout + (size_t)n * DD + kb + l4);
            *(float4*)&Ac[buf][row][l4] = v;
        }
    };

    stage(0, 0);
    __syncthreads();

    const int NCHUNK = DD / CK;   // 4
    for (int c = 0; c < NCHUNK; ++c) {
        if (c + 1 < NCHUNK) stage(c + 1, (c + 1) & 1);
        const int buf = c & 1;
        #pragma unroll
        for (int kc = 0; kc < CK / 4; ++kc) {
            const int k4 = kc << 2;
            float4 af[8];
            #pragma unroll
            for (int i = 0; i < 8; ++i) af[i] = *(const float4*)&Ac[buf][ty * 8 + i][k4];
            float4 bf[4];
            #pragma unroll
            for (int j = 0; j < 4; ++j) bf[j] = *(const float4*)&Wc[buf][tx + 32 * j][k4];
            #pragma unroll
            for (int i = 0; i < 8; ++i) {
                #pragma unroll
                for (int j = 0; j < 4; ++j) {
                    acc[i][j] += af[i].x * bf[j].x;
                    acc[i][j] += af[i].y * bf[j].y;
                    acc[i][j] += af[i].z * bf[j].z;
                    acc[i][j] += af[i].w * bf[j].w;
                }
            }
        }
        __syncthreads();
    }

    const float omb = 1.0f - b;
    #pragma unroll
    for (int i = 0; i < 8; ++i) {
        int n = nb + ty * 8 + i;
        if (n < n_nodes) {
            #pragma unroll
            for (int j = 0; j < 4; ++j) {
                int cidx = tx + 32 * j;
                float viv = vout[(size_t)n * DD + cidx];
                vout[(size_t)n * DD + cidx] = omb * viv + b * acc[i][j];
            }
        }
    }
}

// ===========================================================================
// Fallback atomic-scatter path (used only if ws_size too small)
// ===========================================================================
__global__ __launch_bounds__(256) void k_scatter_edge(
    const float* __restrict__ vfeat, const int* __restrict__ node_idx,
    const int* __restrict__ edge_idx, float* __restrict__ esum,
    float* __restrict__ cnt, int nnz)
{
    int t = blockIdx.x * blockDim.x + threadIdx.x;
    int i = t >> 5;
    if (i >= nnz) return;
    int c = (t & 31) << 2;
    int n = node_idx[i];
    int e = edge_idx[i];
    const float4 v = *(const float4*)(vfeat + (size_t)n * DD + c);
    float* dst = esum + (size_t)e * DD + c;
    atomicAdd(dst + 0, v.x); atomicAdd(dst + 1, v.y);
    atomicAdd(dst + 2, v.z); atomicAdd(dst + 3, v.w);
    if ((t & 31) == 0) atomicAdd(cnt + e, 1.0f);
}

__global__ __launch_bounds__(256) void k_normalize_edge(
    float* __restrict__ efeat, const float* __restrict__ cnt, int n_edges)
{
    int t = blockIdx.x * blockDim.x + threadIdx.x;
    int e = t >> 5;
    if (e >= n_edges) return;
    int c = (t & 31) << 2;
    float inv = 1.0f / fmaxf(cnt[e], 1.0f);
    float4* p = (float4*)(efeat + (size_t)e * DD + c);
    float4 v = *p;
    v.x *= inv; v.y *= inv; v.z *= inv; v.w *= inv;
    *p = v;
}

__global__ __launch_bounds__(256) void k_scatter_node_vi(
    const float* __restrict__ efeat_new, const float* __restrict__ degE,
    const int* __restrict__ node_idx, const int* __restrict__ edge_idx,
    float* __restrict__ h, int nnz)
{
    int t = blockIdx.x * blockDim.x + threadIdx.x;
    int i = t >> 5;
    if (i >= nnz) return;
    int c = (t & 31) << 2;
    int n = node_idx[i];
    int e = edge_idx[i];
    float w = degE[e];
    const float4 v = *(const float4*)(efeat_new + (size_t)e * DD + c);
    float* dst = h + (size_t)n * DD + c;
    atomicAdd(dst + 0, w * v.x); atomicAdd(dst + 1, w * v.y);
    atomicAdd(dst + 2, w * v.z); atomicAdd(dst + 3, w * v.w);
}

__global__ __launch_bounds__(256) void k_h_to_vi(
    float* __restrict__ h, const float* __restrict__ degV,
    const float* __restrict__ vfeat0, const float* __restrict__ alpha,
    int n_nodes)
{
    int t = blockIdx.x * blockDim.x + threadIdx.x;
    int n = t >> 5;
    if (n >= n_nodes) return;
    int c = (t & 31) << 2;
    float a = alpha[0];
    float s = (1.0f - a) * degV[n];
    float4* p = (float4*)(h + (size_t)n * DD + c);
    const float4 f = *(const float4*)(vfeat0 + (size_t)n * DD + c);
    float4 v = *p;
    v.x = s * v.x + a * f.x;
    v.y = s * v.y + a * f.y;
    v.z = s * v.z + a * f.z;
    v.w = s * v.w + a * f.w;
    *p = v;
}

// ===========================================================================
extern "C" void kernel_launch(void* const* d_in, const int* in_sizes, int n_in,
                              void* d_out, int out_size, void* d_ws, size_t ws_size,
                              hipStream_t stream)
{
    const float* vfeat  = (const float*)d_in[0];
    const float* degE   = (const float*)d_in[2];
    const float* degV   = (const float*)d_in[3];
    const float* vfeat0 = (const float*)d_in[4];
    const float* W      = (const float*)d_in[5];
    const float* alpha  = (const float*)d_in[6];
    const float* beta   = (const float*)d_in[7];
    const int* node_idx = (const int*)d_in[8];
    const int* edge_idx = (const int*)d_in[9];

    const int E   = in_sizes[2];
    const int N   = in_sizes[3];
    const int NNZ = in_sizes[8];

    float* vout = (float*)d_out;                   // [N][128]
    float* eout = (float*)d_out + (size_t)N * DD;  // [E][128]

    const size_t need = ((size_t)3 * E + 3 * N + 2 * (size_t)NNZ + 130) * sizeof(int);

    if (ws_size >= need) {
        int* countE  = (int*)d_ws;            // E
        int* countV  = countE + E;            // N
        int* rowptrE = countV + N;            // E+1
        int* rowptrV = rowptrE + E + 1;       // N+1
        int* cursorE = rowptrV + N + 1;       // E
        int* cursorV = cursorE + E;           // N
        int* partE   = cursorV + N;           // 64
        int* partV   = partE + 64;            // 64
        int* adjE    = partV + 64;            // NNZ
        int* adjV    = adjE + NNZ;            // NNZ

        const int nbE = (E + 4095) / 4096;
        const int nbV = (N + 4095) / 4096;

        hipMemsetAsync(countE, 0, (size_t)(E + N) * sizeof(int), stream);

        k_hist<<<(NNZ + 255) / 256, 256, 0, stream>>>(node_idx, edge_idx,
                                                      countE, countV, NNZ);
        k_chunk_sums<<<nbE, 256, 0, stream>>>(countE, E, partE);
        k_chunk_sums<<<nbV, 256, 0, stream>>>(countV, N, partV);
        k_scan_partials2<<<2, 64, 0, stream>>>(partE, nbE, rowptrE + E,
                                               partV, nbV, rowptrV + N);
        k_scan_chunks<<<nbE, 256, 0, stream>>>(countE, E, partE, rowptrE, cursorE);
        k_scan_chunks<<<nbV, 256, 0, stream>>>(countV, N, partV, rowptrV, cursorV);

        k_fill_sliced<<<2048, 256, 0, stream>>>(node_idx, edge_idx,
                                                cursorE, cursorV,
                                                adjE, adjV, NNZ, E, N);

        k_gather_edge<<<((size_t)E * 32 + 255) / 256, 256, 0, stream>>>(
            vfeat, rowptrE, adjE, eout, E);
        k_gather_node_vi<<<((size_t)N * 32 + 255) / 256, 256, 0, stream>>>(
            eout, degE, degV, vfeat0, alpha, rowptrV, adjV, vout, N);
        k_gemm_vi<<<(N + 63) / 64, 256, 0, stream>>>(vout, W, beta, N);
    } else {
        float* cnt = (float*)d_ws;
        hipMemsetAsync(d_out, 0, (size_t)out_size * sizeof(float), stream);
        hipMemsetAsync(cnt, 0, (size_t)E * sizeof(float), stream);
        {
            long long threads = (long long)NNZ * 32;
            int blocks = (int)((threads + 255) / 256);
            k_scatter_edge<<<blocks, 256, 0, stream>>>(vfeat, node_idx, edge_idx,
                                                       eout, cnt, NNZ);
        }
        {
            int blocks = (E * 32 + 255) / 256;
            k_normalize_edge<<<blocks, 256, 0, stream>>>(eout, cnt, E);
        }
        {
            long long threads = (long long)NNZ * 32;
            int blocks = (int)((threads + 255) / 256);
            k_scatter_node_vi<<<blocks, 256, 0, stream>>>(eout, degE, node_idx, edge_idx,
                                                          vout, NNZ);
        }
        k_h_to_vi<<<((size_t)N * 32 + 255) / 256, 256, 0, stream>>>(
            vout, degV, vfeat0, alpha, N);
        k_gemm_vi<<<(N + 63) / 64, 256, 0, stream>>>(vout, W, beta, N);
    }
}

// Round 6
// 408.212 us; speedup vs baseline: 1.0425x; 1.0425x over previous
//
#include <hip/hip_runtime.h>

#define DD 128
#define NSLICE 8
#define CK 32

// ===========================================================================
// CSR build
// ===========================================================================

// ---- histogram + per-item rank: atomicAdd's return IS the rank ------------
__global__ __launch_bounds__(256) void k_hist_rank(
    const int* __restrict__ node_idx,
    const int* __restrict__ edge_idx,
    int* __restrict__ countE,
    int* __restrict__ countV,
    int* __restrict__ rankE,
    int* __restrict__ rankV,
    int nnz)
{
    int i = blockIdx.x * blockDim.x + threadIdx.x;
    if (i >= nnz) return;
    int e = __builtin_nontemporal_load(edge_idx + i);
    int n = __builtin_nontemporal_load(node_idx + i);
    int re = atomicAdd(&countE[e], 1);
    int rv = atomicAdd(&countV[n], 1);
    __builtin_nontemporal_store(re, rankE + i);
    __builtin_nontemporal_store(rv, rankV + i);
}

// plain histogram (fallback tiers)
__global__ __launch_bounds__(256) void k_hist(
    const int* __restrict__ node_idx,
    const int* __restrict__ edge_idx,
    int* __restrict__ countE,
    int* __restrict__ countV,
    int nnz)
{
    int i = blockIdx.x * blockDim.x + threadIdx.x;
    if (i >= nnz) return;
    int e = __builtin_nontemporal_load(edge_idx + i);
    int n = __builtin_nontemporal_load(node_idx + i);
    atomicAdd(&countE[e], 1);
    atomicAdd(&countV[n], 1);
}

__global__ __launch_bounds__(256) void k_chunk_sums(
    const int* __restrict__ cnt, int L, int* __restrict__ partials)
{
    __shared__ int red[256];
    const int tid = threadIdx.x;
    const int base = blockIdx.x * 4096;
    int s = 0;
    for (int j = tid; j < 4096; j += 256) {
        int i = base + j;
        s += (i < L) ? cnt[i] : 0;
    }
    red[tid] = s;
    __syncthreads();
    for (int off = 128; off > 0; off >>= 1) {
        if (tid < off) red[tid] += red[tid + off];
        __syncthreads();
    }
    if (tid == 0) partials[blockIdx.x] = red[0];
}

__global__ void k_scan_partials2(int* __restrict__ pE, int nbE, int* __restrict__ totE,
                                 int* __restrict__ pV, int nbV, int* __restrict__ totV)
{
    if (threadIdx.x != 0) return;
    int* p = (blockIdx.x == 0) ? pE : pV;
    int  nb = (blockIdx.x == 0) ? nbE : nbV;
    int* tot = (blockIdx.x == 0) ? totE : totV;
    int run = 0;
    for (int b = 0; b < nb; ++b) {
        int t = p[b];
        p[b] = run;
        run += t;
    }
    *tot = run;
}

// cursor may be null (rank path needs no cursors)
__global__ __launch_bounds__(256) void k_scan_chunks(
    const int* __restrict__ cnt, int L,
    const int* __restrict__ partials,
    int* __restrict__ rowptr, int* __restrict__ cursor)
{
    __shared__ int tsum[256];
    const int tid = threadIdx.x;
    const int tbase = blockIdx.x * 4096 + tid * 16;
    int loc[16];
    int s = 0;
    #pragma unroll
    for (int k = 0; k < 16; ++k) {
        int i = tbase + k;
        loc[k] = (i < L) ? cnt[i] : 0;
        s += loc[k];
    }
    tsum[tid] = s;
    __syncthreads();
    if (tid == 0) {
        int run = partials[blockIdx.x];
        for (int j = 0; j < 256; ++j) {
            int t = tsum[j];
            tsum[j] = run;
            run += t;
        }
    }
    __syncthreads();
    int run = tsum[tid];
    #pragma unroll
    for (int k = 0; k < 16; ++k) {
        int i = tbase + k;
        if (i < L) {
            rowptr[i] = run;
            if (cursor) cursor[i] = run;
        }
        run += loc[k];
    }
}

// ---- XCD-sliced, atomic-free adjacency fill (rank path) -------------------
__global__ __launch_bounds__(256) void k_fill_sliced_rank(
    const int* __restrict__ node_idx,
    const int* __restrict__ edge_idx,
    const int* __restrict__ rankE,
    const int* __restrict__ rankV,
    const int* __restrict__ rowptrE,
    const int* __restrict__ rowptrV,
    int* __restrict__ adjE, int* __restrict__ adjV,
    int nnz, int E, int N)
{
    const int s = blockIdx.x & (NSLICE - 1);
    const int g = blockIdx.x >> 3;
    const int ngroups = gridDim.x >> 3;
    const int eb = (E + NSLICE - 1) / NSLICE;
    const int nb = (N + NSLICE - 1) / NSLICE;
    const int elo = s * eb, ehi = min(E, elo + eb);
    const int nlo = s * nb, nhi = min(N, nlo + nb);

    const int stride = ngroups * 256;
    for (int i = g * 256 + threadIdx.x; i < nnz; i += stride) {
        int n = __builtin_nontemporal_load(node_idx + i);
        int e = __builtin_nontemporal_load(edge_idx + i);
        if (e >= elo && e < ehi) {
            int p = rowptrE[e] + __builtin_nontemporal_load(rankE + i);
            __builtin_nontemporal_store(n, adjE + p);
        }
        if (n >= nlo && n < nhi) {
            int p = rowptrV[n] + __builtin_nontemporal_load(rankV + i);
            __builtin_nontemporal_store(e, adjV + p);
        }
    }
}

// ---- cursor-based sliced fill (tier-2 fallback) ---------------------------
__global__ __launch_bounds__(256) void k_fill_sliced(
    const int* __restrict__ node_idx,
    const int* __restrict__ edge_idx,
    int* __restrict__ cursorE, int* __restrict__ cursorV,
    int* __restrict__ adjE, int* __restrict__ adjV,
    int nnz, int E, int N)
{
    const int s = blockIdx.x & (NSLICE - 1);
    const int g = blockIdx.x >> 3;
    const int ngroups = gridDim.x >> 3;
    const int eb = (E + NSLICE - 1) / NSLICE;
    const int nb = (N + NSLICE - 1) / NSLICE;
    const int elo = s * eb, ehi = min(E, elo + eb);
    const int nlo = s * nb, nhi = min(N, nlo + nb);

    const int stride = ngroups * 256;
    for (int i = g * 256 + threadIdx.x; i < nnz; i += stride) {
        int n = __builtin_nontemporal_load(node_idx + i);
        int e = __builtin_nontemporal_load(edge_idx + i);
        if (e >= elo && e < ehi) {
            int p = atomicAdd(&cursorE[e], 1);
            adjE[p] = n;
        }
        if (n >= nlo && n < nhi) {
            int p = atomicAdd(&cursorV[n], 1);
            adjV[p] = e;
        }
    }
}

// ===========================================================================
// Gather stages: one wave64 per output row, float2 per lane (no intra-wave
// divergence between sibling row-groups).
// ===========================================================================

// ---- stage 1: efeat_new[e] = mean over incident nodes of vfeat ------------
__global__ __launch_bounds__(256) void k_gather_edge(
    const float* __restrict__ vfeat,
    const int* __restrict__ rowptrE,
    const int* __restrict__ adjE,
    float* __restrict__ efeat,
    int n_edges)
{
    const int row = (blockIdx.x * blockDim.x + threadIdx.x) >> 6;
    if (row >= n_edges) return;
    const int lane = threadIdx.x & 63;
    const int beg = rowptrE[row];
    const int len = rowptrE[row + 1] - beg;

    const float2* vb = (const float2*)vfeat + lane;
    float2 c0 = {0,0}, c1 = {0,0}, c2 = {0,0}, c3 = {0,0};

    int k = 0;
    for (; k + 4 <= len; k += 4) {
        int e0 = adjE[beg + k + 0];
        int e1 = adjE[beg + k + 1];
        int e2 = adjE[beg + k + 2];
        int e3 = adjE[beg + k + 3];
        float2 r0 = vb[(size_t)e0 * 64];
        float2 r1 = vb[(size_t)e1 * 64];
        float2 r2 = vb[(size_t)e2 * 64];
        float2 r3 = vb[(size_t)e3 * 64];
        c0.x += r0.x; c0.y += r0.y;
        c1.x += r1.x; c1.y += r1.y;
        c2.x += r2.x; c2.y += r2.y;
        c3.x += r3.x; c3.y += r3.y;
    }
    for (; k < len; ++k) {
        int e0 = adjE[beg + k];
        float2 r0 = vb[(size_t)e0 * 64];
        c0.x += r0.x; c0.y += r0.y;
    }
    float inv = (len > 0) ? 1.0f / (float)len : 0.0f;
    float2 o;
    o.x = (c0.x + c1.x + c2.x + c3.x) * inv;
    o.y = (c0.y + c1.y + c2.y + c3.y) * inv;
    ((float2*)(efeat + (size_t)row * DD))[lane] = o;
}

// ---- stage 2 fused: vi[n] = (1-a)*degV[n]*sum(degE[e]*efeat[e]) + a*vfeat0[n]
__global__ __launch_bounds__(256) void k_gather_node_vi(
    const float* __restrict__ efeat,
    const float* __restrict__ degE,
    const float* __restrict__ degV,
    const float* __restrict__ vfeat0,
    const float* __restrict__ alpha,
    const int* __restrict__ rowptrV,
    const int* __restrict__ adjV,
    float* __restrict__ vi,
    int n_nodes)
{
    const int row = (blockIdx.x * blockDim.x + threadIdx.x) >> 6;
    if (row >= n_nodes) return;
    const int lane = threadIdx.x & 63;
    const int beg = rowptrV[row];
    const int len = rowptrV[row + 1] - beg;

    const float2* eb = (const float2*)efeat + lane;
    float2 c0 = {0,0}, c1 = {0,0}, c2 = {0,0}, c3 = {0,0};

    int k = 0;
    for (; k + 4 <= len; k += 4) {
        int e0 = adjV[beg + k + 0];
        int e1 = adjV[beg + k + 1];
        int e2 = adjV[beg + k + 2];
        int e3 = adjV[beg + k + 3];
        float w0 = degE[e0], w1 = degE[e1], w2 = degE[e2], w3 = degE[e3];
        float2 r0 = eb[(size_t)e0 * 64];
        float2 r1 = eb[(size_t)e1 * 64];
        float2 r2 = eb[(size_t)e2 * 64];
        float2 r3 = eb[(size_t)e3 * 64];
        c0.x += w0 * r0.x; c0.y += w0 * r0.y;
        c1.x += w1 * r1.x; c1.y += w1 * r1.y;
        c2.x += w2 * r2.x; c2.y += w2 * r2.y;
        c3.x += w3 * r3.x; c3.y += w3 * r3.y;
    }
    for (; k < len; ++k) {
        int e0 = adjV[beg + k];
        float w0 = degE[e0];
        float2 r0 = eb[(size_t)e0 * 64];
        c0.x += w0 * r0.x; c0.y += w0 * r0.y;
    }
    const float a = alpha[0];
    const float s = (1.0f - a) * degV[row];
    const float2 f = ((const float2*)(vfeat0 + (size_t)row * DD))[lane];
    float2 o;
    o.x = s * (c0.x + c1.x + c2.x + c3.x) + a * f.x;
    o.y = s * (c0.y + c1.y + c2.y + c3.y) + a * f.y;
    ((float2*)(vi + (size_t)row * DD))[lane] = o;
}

// ---------------------------------------------------------------------------
// K-chunked, double-buffered epilogue GEMM, in place on vout (vi -> v).
// LDS = 52 KB -> 3 blocks/CU.
// ---------------------------------------------------------------------------
__global__ __launch_bounds__(256) void k_gemm_vi(
    float* __restrict__ vout,           // in: vi, out: v   [N][128]
    const float* __restrict__ W,        // [128][128]
    const float* __restrict__ beta,
    int n_nodes)
{
    __shared__ float Wc[2][128][CK + 4];
    __shared__ float Ac[2][64][CK];

    const int tid = threadIdx.x;
    const float b = beta[0];
    const int nb = blockIdx.x * 64;

    const int tx = tid & 31;
    const int ty = tid >> 5;

    float acc[8][4];
    #pragma unroll
    for (int i = 0; i < 8; ++i)
        #pragma unroll
        for (int j = 0; j < 4; ++j) acc[i][j] = 0.0f;

    auto stage = [&](int chunk, int buf) {
        const int kb = chunk * CK;
        #pragma unroll
        for (int p = 0; p < 4; ++p) {
            int idx = tid + p * 256;
            int row = idx >> 3;
            int l4 = (idx & 7) << 2;
            *(float4*)&Wc[buf][row][l4] = *(const float4*)(W + row * DD + kb + l4);
        }
        #pragma unroll
        for (int p = 0; p < 2; ++p) {
            int idx = tid + p * 256;
            int row = idx >> 3;
            int l4 = (idx & 7) << 2;
            int n = nb + row;
            float4 v = {0, 0, 0, 0};
            if (n < n_nodes) v = *(const float4*)(vout + (size_t)n * DD + kb + l4);
            *(float4*)&Ac[buf][row][l4] = v;
        }
    };

    stage(0, 0);
    __syncthreads();

    const int NCHUNK = DD / CK;   // 4
    for (int c = 0; c < NCHUNK; ++c) {
        if (c + 1 < NCHUNK) stage(c + 1, (c + 1) & 1);
        const int buf = c & 1;
        #pragma unroll
        for (int kc = 0; kc < CK / 4; ++kc) {
            const int k4 = kc << 2;
            float4 af[8];
            #pragma unroll
            for (int i = 0; i < 8; ++i) af[i] = *(const float4*)&Ac[buf][ty * 8 + i][k4];
            float4 bf[4];
            #pragma unroll
            for (int j = 0; j < 4; ++j) bf[j] = *(const float4*)&Wc[buf][tx + 32 * j][k4];
            #pragma unroll
            for (int i = 0; i < 8; ++i) {
                #pragma unroll
                for (int j = 0; j < 4; ++j) {
                    acc[i][j] += af[i].x * bf[j].x;
                    acc[i][j] += af[i].y * bf[j].y;
                    acc[i][j] += af[i].z * bf[j].z;
                    acc[i][j] += af[i].w * bf[j].w;
                }
            }
        }
        __syncthreads();
    }

    const float omb = 1.0f - b;
    #pragma unroll
    for (int i = 0; i < 8; ++i) {
        int n = nb + ty * 8 + i;
        if (n < n_nodes) {
            #pragma unroll
            for (int j = 0; j < 4; ++j) {
                int cidx = tx + 32 * j;
                float viv = vout[(size_t)n * DD + cidx];
                vout[(size_t)n * DD + cidx] = omb * viv + b * acc[i][j];
            }
        }
    }
}

// ===========================================================================
// Tier-3 fallback: atomic-scatter path
// ===========================================================================
__global__ __launch_bounds__(256) void k_scatter_edge(
    const float* __restrict__ vfeat, const int* __restrict__ node_idx,
    const int* __restrict__ edge_idx, float* __restrict__ esum,
    float* __restrict__ cnt, int nnz)
{
    int t = blockIdx.x * blockDim.x + threadIdx.x;
    int i = t >> 5;
    if (i >= nnz) return;
    int c = (t & 31) << 2;
    int n = node_idx[i];
    int e = edge_idx[i];
    const float4 v = *(const float4*)(vfeat + (size_t)n * DD + c);
    float* dst = esum + (size_t)e * DD + c;
    atomicAdd(dst + 0, v.x); atomicAdd(dst + 1, v.y);
    atomicAdd(dst + 2, v.z); atomicAdd(dst + 3, v.w);
    if ((t & 31) == 0) atomicAdd(cnt + e, 1.0f);
}

__global__ __launch_bounds__(256) void k_normalize_edge(
    float* __restrict__ efeat, const float* __restrict__ cnt, int n_edges)
{
    int t = blockIdx.x * blockDim.x + threadIdx.x;
    int e = t >> 5;
    if (e >= n_edges) return;
    int c = (t & 31) << 2;
    float inv = 1.0f / fmaxf(cnt[e], 1.0f);
    float4* p = (float4*)(efeat + (size_t)e * DD + c);
    float4 v = *p;
    v.x *= inv; v.y *= inv; v.z *= inv; v.w *= inv;
    *p = v;
}

__global__ __launch_bounds__(256) void k_scatter_node_vi(
    const float* __restrict__ efeat_new, const float* __restrict__ degE,
    const int* __restrict__ node_idx, const int* __restrict__ edge_idx,
    float* __restrict__ h, int nnz)
{
    int t = blockIdx.x * blockDim.x + threadIdx.x;
    int i = t >> 5;
    if (i >= nnz) return;
    int c = (t & 31) << 2;
    int n = node_idx[i];
    int e = edge_idx[i];
    float w = degE[e];
    const float4 v = *(const float4*)(efeat_new + (size_t)e * DD + c);
    float* dst = h + (size_t)n * DD + c;
    atomicAdd(dst + 0, w * v.x); atomicAdd(dst + 1, w * v.y);
    atomicAdd(dst + 2, w * v.z); atomicAdd(dst + 3, w * v.w);
}

__global__ __launch_bounds__(256) void k_h_to_vi(
    float* __restrict__ h, const float* __restrict__ degV,
    const float* __restrict__ vfeat0, const float* __restrict__ alpha,
    int n_nodes)
{
    int t = blockIdx.x * blockDim.x + threadIdx.x;
    int n = t >> 5;
    if (n >= n_nodes) return;
    int c = (t & 31) << 2;
    float a = alpha[0];
    float s = (1.0f - a) * degV[n];
    float4* p = (float4*)(h + (size_t)n * DD + c);
    const float4 f = *(const float4*)(vfeat0 + (size_t)n * DD + c);
    float4 v = *p;
    v.x = s * v.x + a * f.x;
    v.y = s * v.y + a * f.y;
    v.z = s * v.z + a * f.z;
    v.w = s * v.w + a * f.w;
    *p = v;
}

// ===========================================================================
extern "C" void kernel_launch(void* const* d_in, const int* in_sizes, int n_in,
                              void* d_out, int out_size, void* d_ws, size_t ws_size,
                              hipStream_t stream)
{
    const float* vfeat  = (const float*)d_in[0];
    const float* degE   = (const float*)d_in[2];
    const float* degV   = (const float*)d_in[3];
    const float* vfeat0 = (const float*)d_in[4];
    const float* W      = (const float*)d_in[5];
    const float* alpha  = (const float*)d_in[6];
    const float* beta   = (const float*)d_in[7];
    const int* node_idx = (const int*)d_in[8];
    const int* edge_idx = (const int*)d_in[9];

    const int E   = in_sizes[2];
    const int N   = in_sizes[3];
    const int NNZ = in_sizes[8];

    float* vout = (float*)d_out;                   // [N][128]
    float* eout = (float*)d_out + (size_t)N * DD;  // [E][128]

    const int nbE = (E + 4095) / 4096;
    const int nbV = (N + 4095) / 4096;

    // tier-1 (rank path): 2E + 2N + 4*NNZ + 130 ints
    const size_t need_rank = ((size_t)2 * E + 2 * N + 4 * (size_t)NNZ + 130) * sizeof(int);
    // tier-2 (cursor path): 3E + 3N + 2*NNZ + 130 ints
    const size_t need_cur  = ((size_t)3 * E + 3 * N + 2 * (size_t)NNZ + 130) * sizeof(int);

    if (ws_size >= need_rank) {
        int* countE  = (int*)d_ws;            // E
        int* countV  = countE + E;            // N
        int* rowptrE = countV + N;            // E+1
        int* rowptrV = rowptrE + E + 1;       // N+1
        int* partE   = rowptrV + N + 1;       // 64
        int* partV   = partE + 64;            // 64
        int* rankE   = partV + 64;            // NNZ
        int* rankV   = rankE + NNZ;           // NNZ
        int* adjE    = rankV + NNZ;           // NNZ
        int* adjV    = adjE + NNZ;            // NNZ

        hipMemsetAsync(countE, 0, (size_t)(E + N) * sizeof(int), stream);

        k_hist_rank<<<(NNZ + 255) / 256, 256, 0, stream>>>(
            node_idx, edge_idx, countE, countV, rankE, rankV, NNZ);
        k_chunk_sums<<<nbE, 256, 0, stream>>>(countE, E, partE);
        k_chunk_sums<<<nbV, 256, 0, stream>>>(countV, N, partV);
        k_scan_partials2<<<2, 64, 0, stream>>>(partE, nbE, rowptrE + E,
                                               partV, nbV, rowptrV + N);
        k_scan_chunks<<<nbE, 256, 0, stream>>>(countE, E, partE, rowptrE, nullptr);
        k_scan_chunks<<<nbV, 256, 0, stream>>>(countV, N, partV, rowptrV, nullptr);

        k_fill_sliced_rank<<<2048, 256, 0, stream>>>(
            node_idx, edge_idx, rankE, rankV, rowptrE, rowptrV,
            adjE, adjV, NNZ, E, N);

        k_gather_edge<<<((size_t)E * 64 + 255) / 256, 256, 0, stream>>>(
            vfeat, rowptrE, adjE, eout, E);
        k_gather_node_vi<<<((size_t)N * 64 + 255) / 256, 256, 0, stream>>>(
            eout, degE, degV, vfeat0, alpha, rowptrV, adjV, vout, N);
        k_gemm_vi<<<(N + 63) / 64, 256, 0, stream>>>(vout, W, beta, N);
    } else if (ws_size >= need_cur) {
        int* countE  = (int*)d_ws;            // E
        int* countV  = countE + E;            // N
        int* rowptrE = countV + N;            // E+1
        int* rowptrV = rowptrE + E + 1;       // N+1
        int* cursorE = rowptrV + N + 1;       // E
        int* cursorV = cursorE + E;           // N
        int* partE   = cursorV + N;           // 64
        int* partV   = partE + 64;            // 64
        int* adjE    = partV + 64;            // NNZ
        int* adjV    = adjE + NNZ;            // NNZ

        hipMemsetAsync(countE, 0, (size_t)(E + N) * sizeof(int), stream);

        k_hist<<<(NNZ + 255) / 256, 256, 0, stream>>>(node_idx, edge_idx,
                                                      countE, countV, NNZ);
        k_chunk_sums<<<nbE, 256, 0, stream>>>(countE, E, partE);
        k_chunk_sums<<<nbV, 256, 0, stream>>>(countV, N, partV);
        k_scan_partials2<<<2, 64, 0, stream>>>(partE, nbE, rowptrE + E,
                                               partV, nbV, rowptrV + N);
        k_scan_chunks<<<nbE, 256, 0, stream>>>(countE, E, partE, rowptrE, cursorE);
        k_scan_chunks<<<nbV, 256, 0, stream>>>(countV, N, partV, rowptrV, cursorV);

        k_fill_sliced<<<2048, 256, 0, stream>>>(node_idx, edge_idx,
                                                cursorE, cursorV,
                                                adjE, adjV, NNZ, E, N);

        k_gather_edge<<<((size_t)E * 64 + 255) / 256, 256, 0, stream>>>(
            vfeat, rowptrE, adjE, eout, E);
        k_gather_node_vi<<<((size_t)N * 64 + 255) / 256, 256, 0, stream>>>(
            eout, degE, degV, vfeat0, alpha, rowptrV, adjV, vout, N);
        k_gemm_vi<<<(N + 63) / 64, 256, 0, stream>>>(vout, W, beta, N);
    } else {
        float* cnt = (float*)d_ws;
        hipMemsetAsync(d_out, 0, (size_t)out_size * sizeof(float), stream);
        hipMemsetAsync(cnt, 0, (size_t)E * sizeof(float), stream);
        {
            long long threads = (long long)NNZ * 32;
            int blocks = (int)((threads + 255) / 256);
            k_scatter_edge<<<blocks, 256, 0, stream>>>(vfeat, node_idx, edge_idx,
                                                       eout, cnt, NNZ);
        }
        {
            int blocks = (E * 32 + 255) / 256;
            k_normalize_edge<<<blocks, 256, 0, stream>>>(eout, cnt, E);
        }
        {
            long long threads = (long long)NNZ * 32;
            int blocks = (int)((threads + 255) / 256);
            k_scatter_node_vi<<<blocks, 256, 0, stream>>>(eout, degE, node_idx, edge_idx,
                                                          vout, NNZ);
        }
        k_h_to_vi<<<((size_t)N * 32 + 255) / 256, 256, 0, stream>>>(
            vout, degV, vfeat0, alpha, N);
        k_gemm_vi<<<(N + 63) / 64, 256, 0, stream>>>(vout, W, beta, N);
    }
}

// Round 7
// 380.052 us; speedup vs baseline: 1.1198x; 1.0741x over previous
//
#include <hip/hip_runtime.h>

#define DD 128
#define NSLICE 8
#define CK 32
#define NCHE 32
#define NCHV 16

// ===========================================================================
// Tier-1 CSR build: LDS-privatized counting sort (zero global atomics)
// ===========================================================================

// ---- per-chunk histogram + local ranks for edge_idx (E <= 20000) ----------
__global__ __launch_bounds__(1024) void k_cnt_rank_E(
    const int* __restrict__ idx,
    unsigned short* __restrict__ lrank,     // [NNZ]
    unsigned short* __restrict__ hist,      // [NCHE][E]
    int nnz, int ci, int E)
{
    __shared__ unsigned int lh[10000];      // packed 2xu16, 20000 segs max
    const int c = blockIdx.x;
    const int tid = threadIdx.x;
    const int W = (E + 1) >> 1;
    for (int w = tid; w < W; w += 1024) lh[w] = 0u;
    __syncthreads();

    const int beg = c * ci;
    const int end = min(nnz, beg + ci);
    for (int ib = beg; ib < end; ib += 1024 * 8) {
        int v[8]; bool m[8];
        #pragma unroll
        for (int t = 0; t < 8; ++t) {
            int ii = ib + t * 1024 + tid;
            m[t] = ii < end;
            v[t] = m[t] ? __builtin_nontemporal_load(idx + ii) : 0;
        }
        #pragma unroll
        for (int t = 0; t < 8; ++t) {
            if (m[t]) {
                int s = v[t];
                unsigned sh = (s & 1) << 4;
                unsigned ret = atomicAdd(&lh[s >> 1], 1u << sh);
                unsigned lr = (ret >> sh) & 0xffffu;
                __builtin_nontemporal_store((unsigned short)lr,
                                            lrank + ib + t * 1024 + tid);
            }
        }
    }
    __syncthreads();
    unsigned int* hp = (unsigned int*)(hist + (size_t)c * E);  // E even
    for (int w = tid; w < W; w += 1024) hp[w] = lh[w];
}

// ---- per-chunk histogram + local ranks for node_idx (N <= 100000) ---------
// grid (NCHV, 2): blockIdx.y = pass, pass p owns segs [p*50000, min(N,(p+1)*50000))
__global__ __launch_bounds__(1024) void k_cnt_rank_V(
    const int* __restrict__ idx,
    unsigned short* __restrict__ lrank,     // [NNZ]
    unsigned short* __restrict__ hist,      // [NCHV][N]
    int nnz, int ci, int N)
{
    __shared__ unsigned int lh[25000];      // packed 2xu16, 50000 segs per pass
    const int c = blockIdx.x;
    const int lo = blockIdx.y * 50000;
    const int hi = min(N, lo + 50000);
    const int span = hi - lo;
    const int tid = threadIdx.x;
    const int W = (span + 1) >> 1;
    for (int w = tid; w < W; w += 1024) lh[w] = 0u;
    __syncthreads();

    const int beg = c * ci;
    const int end = min(nnz, beg + ci);
    for (int ib = beg; ib < end; ib += 1024 * 8) {
        int v[8]; bool m[8];
        #pragma unroll
        for (int t = 0; t < 8; ++t) {
            int ii = ib + t * 1024 + tid;
            m[t] = ii < end;
            v[t] = m[t] ? __builtin_nontemporal_load(idx + ii) : -1;
        }
        #pragma unroll
        for (int t = 0; t < 8; ++t) {
            int s = v[t] - lo;
            if (m[t] && s >= 0 && s < span) {
                unsigned sh = (s & 1) << 4;
                unsigned ret = atomicAdd(&lh[s >> 1], 1u << sh);
                unsigned lr = (ret >> sh) & 0xffffu;
                __builtin_nontemporal_store((unsigned short)lr,
                                            lrank + ib + t * 1024 + tid);
            }
        }
    }
    __syncthreads();
    unsigned int* hp = (unsigned int*)(hist + (size_t)c * N + lo);  // N, lo even
    for (int w = tid; w < W; w += 1024) hp[w] = lh[w];
}

// ---- per-segment exclusive prefix over chunks; emits count ----------------
__global__ __launch_bounds__(256) void k_sum_prefix(
    const unsigned short* __restrict__ hist,   // [nchunk][nseg]
    unsigned int* __restrict__ base,           // [nchunk][nseg]
    int* __restrict__ count,                   // [nseg]
    int nseg, int nchunk)
{
    int s = blockIdx.x * blockDim.x + threadIdx.x;
    if (s >= nseg) return;
    unsigned run = 0;
    for (int c = 0; c < nchunk; ++c) {
        base[(size_t)c * nseg + s] = run;
        run += hist[(size_t)c * nseg + s];
    }
    count[s] = (int)run;
}

// ---- XCD-sliced, fully atomic-free adjacency fill -------------------------
__global__ __launch_bounds__(256) void k_fill_cs(
    const int* __restrict__ node_idx,
    const int* __restrict__ edge_idx,
    const unsigned short* __restrict__ lrankE,
    const unsigned short* __restrict__ lrankV,
    const unsigned int* __restrict__ baseE,
    const unsigned int* __restrict__ baseV,
    const int* __restrict__ rowptrE,
    const int* __restrict__ rowptrV,
    int* __restrict__ adjE, int* __restrict__ adjV,
    int nnz, int E, int N, int ciE, int ciV)
{
    const int s = blockIdx.x & (NSLICE - 1);
    const int g = blockIdx.x >> 3;
    const int ngroups = gridDim.x >> 3;
    const int eb = (E + NSLICE - 1) / NSLICE;
    const int nb = (N + NSLICE - 1) / NSLICE;
    const int elo = s * eb, ehi = min(E, elo + eb);
    const int nlo = s * nb, nhi = min(N, nlo + nb);

    const int stride = ngroups * 256;
    for (int i = g * 256 + threadIdx.x; i < nnz; i += stride) {
        int n = __builtin_nontemporal_load(node_idx + i);
        int e = __builtin_nontemporal_load(edge_idx + i);
        if (e >= elo && e < ehi) {
            int ce = (int)((unsigned)i / (unsigned)ciE);
            int p = rowptrE[e] + (int)baseE[(size_t)ce * E + e]
                  + (int)__builtin_nontemporal_load(lrankE + i);
            __builtin_nontemporal_store(n, adjE + p);
        }
        if (n >= nlo && n < nhi) {
            int cv = (int)((unsigned)i / (unsigned)ciV);
            int p = rowptrV[n] + (int)baseV[(size_t)cv * N + n]
                  + (int)__builtin_nontemporal_load(lrankV + i);
            __builtin_nontemporal_store(e, adjV + p);
        }
    }
}

// ===========================================================================
// Shared scan infrastructure
// ===========================================================================

__global__ __launch_bounds__(256) void k_chunk_sums(
    const int* __restrict__ cnt, int L, int* __restrict__ partials)
{
    __shared__ int red[256];
    const int tid = threadIdx.x;
    const int base = blockIdx.x * 4096;
    int s = 0;
    for (int j = tid; j < 4096; j += 256) {
        int i = base + j;
        s += (i < L) ? cnt[i] : 0;
    }
    red[tid] = s;
    __syncthreads();
    for (int off = 128; off > 0; off >>= 1) {
        if (tid < off) red[tid] += red[tid + off];
        __syncthreads();
    }
    if (tid == 0) partials[blockIdx.x] = red[0];
}

__global__ void k_scan_partials2(int* __restrict__ pE, int nbE, int* __restrict__ totE,
                                 int* __restrict__ pV, int nbV, int* __restrict__ totV)
{
    if (threadIdx.x != 0) return;
    int* p = (blockIdx.x == 0) ? pE : pV;
    int  nb = (blockIdx.x == 0) ? nbE : nbV;
    int* tot = (blockIdx.x == 0) ? totE : totV;
    int run = 0;
    for (int b = 0; b < nb; ++b) {
        int t = p[b];
        p[b] = run;
        run += t;
    }
    *tot = run;
}

__global__ __launch_bounds__(256) void k_scan_chunks(
    const int* __restrict__ cnt, int L,
    const int* __restrict__ partials,
    int* __restrict__ rowptr, int* __restrict__ cursor)
{
    __shared__ int tsum[256];
    const int tid = threadIdx.x;
    const int tbase = blockIdx.x * 4096 + tid * 16;
    int loc[16];
    int s = 0;
    #pragma unroll
    for (int k = 0; k < 16; ++k) {
        int i = tbase + k;
        loc[k] = (i < L) ? cnt[i] : 0;
        s += loc[k];
    }
    tsum[tid] = s;
    __syncthreads();
    if (tid == 0) {
        int run = partials[blockIdx.x];
        for (int j = 0; j < 256; ++j) {
            int t = tsum[j];
            tsum[j] = run;
            run += t;
        }
    }
    __syncthreads();
    int run = tsum[tid];
    #pragma unroll
    for (int k = 0; k < 16; ++k) {
        int i = tbase + k;
        if (i < L) {
            rowptr[i] = run;
            if (cursor) cursor[i] = run;
        }
        run += loc[k];
    }
}

// ===========================================================================
// Fallback-tier CSR kernels
// ===========================================================================

__global__ __launch_bounds__(256) void k_hist_rank(
    const int* __restrict__ node_idx,
    const int* __restrict__ edge_idx,
    int* __restrict__ countE, int* __restrict__ countV,
    int* __restrict__ rankE, int* __restrict__ rankV, int nnz)
{
    int i = blockIdx.x * blockDim.x + threadIdx.x;
    if (i >= nnz) return;
    int e = __builtin_nontemporal_load(edge_idx + i);
    int n = __builtin_nontemporal_load(node_idx + i);
    int re = atomicAdd(&countE[e], 1);
    int rv = atomicAdd(&countV[n], 1);
    __builtin_nontemporal_store(re, rankE + i);
    __builtin_nontemporal_store(rv, rankV + i);
}

__global__ __launch_bounds__(256) void k_hist(
    const int* __restrict__ node_idx,
    const int* __restrict__ edge_idx,
    int* __restrict__ countE, int* __restrict__ countV, int nnz)
{
    int i = blockIdx.x * blockDim.x + threadIdx.x;
    if (i >= nnz) return;
    atomicAdd(&countE[__builtin_nontemporal_load(edge_idx + i)], 1);
    atomicAdd(&countV[__builtin_nontemporal_load(node_idx + i)], 1);
}

__global__ __launch_bounds__(256) void k_fill_sliced_rank(
    const int* __restrict__ node_idx,
    const int* __restrict__ edge_idx,
    const int* __restrict__ rankE, const int* __restrict__ rankV,
    const int* __restrict__ rowptrE, const int* __restrict__ rowptrV,
    int* __restrict__ adjE, int* __restrict__ adjV,
    int nnz, int E, int N)
{
    const int s = blockIdx.x & (NSLICE - 1);
    const int g = blockIdx.x >> 3;
    const int ngroups = gridDim.x >> 3;
    const int eb = (E + NSLICE - 1) / NSLICE;
    const int nb = (N + NSLICE - 1) / NSLICE;
    const int elo = s * eb, ehi = min(E, elo + eb);
    const int nlo = s * nb, nhi = min(N, nlo + nb);

    const int stride = ngroups * 256;
    for (int i = g * 256 + threadIdx.x; i < nnz; i += stride) {
        int n = __builtin_nontemporal_load(node_idx + i);
        int e = __builtin_nontemporal_load(edge_idx + i);
        if (e >= elo && e < ehi) {
            int p = rowptrE[e] + __builtin_nontemporal_load(rankE + i);
            __builtin_nontemporal_store(n, adjE + p);
        }
        if (n >= nlo && n < nhi) {
            int p = rowptrV[n] + __builtin_nontemporal_load(rankV + i);
            __builtin_nontemporal_store(e, adjV + p);
        }
    }
}

__global__ __launch_bounds__(256) void k_fill_sliced(
    const int* __restrict__ node_idx,
    const int* __restrict__ edge_idx,
    int* __restrict__ cursorE, int* __restrict__ cursorV,
    int* __restrict__ adjE, int* __restrict__ adjV,
    int nnz, int E, int N)
{
    const int s = blockIdx.x & (NSLICE - 1);
    const int g = blockIdx.x >> 3;
    const int ngroups = gridDim.x >> 3;
    const int eb = (E + NSLICE - 1) / NSLICE;
    const int nb = (N + NSLICE - 1) / NSLICE;
    const int elo = s * eb, ehi = min(E, elo + eb);
    const int nlo = s * nb, nhi = min(N, nlo + nb);

    const int stride = ngroups * 256;
    for (int i = g * 256 + threadIdx.x; i < nnz; i += stride) {
        int n = __builtin_nontemporal_load(node_idx + i);
        int e = __builtin_nontemporal_load(edge_idx + i);
        if (e >= elo && e < ehi) {
            int p = atomicAdd(&cursorE[e], 1);
            adjE[p] = n;
        }
        if (n >= nlo && n < nhi) {
            int p = atomicAdd(&cursorV[n], 1);
            adjV[p] = e;
        }
    }
}

// ===========================================================================
// Gather stages (wave64 per row, float2 per lane)
// ===========================================================================

__global__ __launch_bounds__(256) void k_gather_edge(
    const float* __restrict__ vfeat,
    const int* __restrict__ rowptrE,
    const int* __restrict__ adjE,
    float* __restrict__ efeat,
    int n_edges)
{
    const int row = (blockIdx.x * blockDim.x + threadIdx.x) >> 6;
    if (row >= n_edges) return;
    const int lane = threadIdx.x & 63;
    const int beg = rowptrE[row];
    const int len = rowptrE[row + 1] - beg;

    const float2* vb = (const float2*)vfeat + lane;
    float2 c0 = {0,0}, c1 = {0,0}, c2 = {0,0}, c3 = {0,0};

    int k = 0;
    for (; k + 4 <= len; k += 4) {
        int e0 = adjE[beg + k + 0];
        int e1 = adjE[beg + k + 1];
        int e2 = adjE[beg + k + 2];
        int e3 = adjE[beg + k + 3];
        float2 r0 = vb[(size_t)e0 * 64];
        float2 r1 = vb[(size_t)e1 * 64];
        float2 r2 = vb[(size_t)e2 * 64];
        float2 r3 = vb[(size_t)e3 * 64];
        c0.x += r0.x; c0.y += r0.y;
        c1.x += r1.x; c1.y += r1.y;
        c2.x += r2.x; c2.y += r2.y;
        c3.x += r3.x; c3.y += r3.y;
    }
    for (; k < len; ++k) {
        int e0 = adjE[beg + k];
        float2 r0 = vb[(size_t)e0 * 64];
        c0.x += r0.x; c0.y += r0.y;
    }
    float inv = (len > 0) ? 1.0f / (float)len : 0.0f;
    float2 o;
    o.x = (c0.x + c1.x + c2.x + c3.x) * inv;
    o.y = (c0.y + c1.y + c2.y + c3.y) * inv;
    ((float2*)(efeat + (size_t)row * DD))[lane] = o;
}

__global__ __launch_bounds__(256) void k_gather_node_vi(
    const float* __restrict__ efeat,
    const float* __restrict__ degE,
    const float* __restrict__ degV,
    const float* __restrict__ vfeat0,
    const float* __restrict__ alpha,
    const int* __restrict__ rowptrV,
    const int* __restrict__ adjV,
    float* __restrict__ vi,
    int n_nodes)
{
    const int row = (blockIdx.x * blockDim.x + threadIdx.x) >> 6;
    if (row >= n_nodes) return;
    const int lane = threadIdx.x & 63;
    const int beg = rowptrV[row];
    const int len = rowptrV[row + 1] - beg;

    const float2* eb = (const float2*)efeat + lane;
    float2 c0 = {0,0}, c1 = {0,0}, c2 = {0,0}, c3 = {0,0};

    int k = 0;
    for (; k + 4 <= len; k += 4) {
        int e0 = adjV[beg + k + 0];
        int e1 = adjV[beg + k + 1];
        int e2 = adjV[beg + k + 2];
        int e3 = adjV[beg + k + 3];
        float w0 = degE[e0], w1 = degE[e1], w2 = degE[e2], w3 = degE[e3];
        float2 r0 = eb[(size_t)e0 * 64];
        float2 r1 = eb[(size_t)e1 * 64];
        float2 r2 = eb[(size_t)e2 * 64];
        float2 r3 = eb[(size_t)e3 * 64];
        c0.x += w0 * r0.x; c0.y += w0 * r0.y;
        c1.x += w1 * r1.x; c1.y += w1 * r1.y;
        c2.x += w2 * r2.x; c2.y += w2 * r2.y;
        c3.x += w3 * r3.x; c3.y += w3 * r3.y;
    }
    for (; k < len; ++k) {
        int e0 = adjV[beg + k];
        float w0 = degE[e0];
        float2 r0 = eb[(size_t)e0 * 64];
        c0.x += w0 * r0.x; c0.y += w0 * r0.y;
    }
    const float a = alpha[0];
    const float s = (1.0f - a) * degV[row];
    const float2 f = ((const float2*)(vfeat0 + (size_t)row * DD))[lane];
    float2 o;
    o.x = s * (c0.x + c1.x + c2.x + c3.x) + a * f.x;
    o.y = s * (c0.y + c1.y + c2.y + c3.y) + a * f.y;
    ((float2*)(vi + (size_t)row * DD))[lane] = o;
}

// ---------------------------------------------------------------------------
// K-chunked, double-buffered epilogue GEMM, in place on vout (vi -> v).
// ---------------------------------------------------------------------------
__global__ __launch_bounds__(256) void k_gemm_vi(
    float* __restrict__ vout,
    const float* __restrict__ W,
    const float* __restrict__ beta,
    int n_nodes)
{
    __shared__ float Wc[2][128][CK + 4];
    __shared__ float Ac[2][64][CK];

    const int tid = threadIdx.x;
    const float b = beta[0];
    const int nb = blockIdx.x * 64;

    const int tx = tid & 31;
    const int ty = tid >> 5;

    float acc[8][4];
    #pragma unroll
    for (int i = 0; i < 8; ++i)
        #pragma unroll
        for (int j = 0; j < 4; ++j) acc[i][j] = 0.0f;

    auto stage = [&](int chunk, int buf) {
        const int kb = chunk * CK;
        #pragma unroll
        for (int p = 0; p < 4; ++p) {
            int idx = tid + p * 256;
            int row = idx >> 3;
            int l4 = (idx & 7) << 2;
            *(float4*)&Wc[buf][row][l4] = *(const float4*)(W + row * DD + kb + l4);
        }
        #pragma unroll
        for (int p = 0; p < 2; ++p) {
            int idx = tid + p * 256;
            int row = idx >> 3;
            int l4 = (idx & 7) << 2;
            int n = nb + row;
            float4 v = {0, 0, 0, 0};
            if (n < n_nodes) v = *(const float4*)(vout + (size_t)n * DD + kb + l4);
            *(float4*)&Ac[buf][row][l4] = v;
        }
    };

    stage(0, 0);
    __syncthreads();

    const int NCHUNK = DD / CK;
    for (int c = 0; c < NCHUNK; ++c) {
        if (c + 1 < NCHUNK) stage(c + 1, (c + 1) & 1);
        const int buf = c & 1;
        #pragma unroll
        for (int kc = 0; kc < CK / 4; ++kc) {
            const int k4 = kc << 2;
            float4 af[8];
            #pragma unroll
            for (int i = 0; i < 8; ++i) af[i] = *(const float4*)&Ac[buf][ty * 8 + i][k4];
            float4 bf[4];
            #pragma unroll
            for (int j = 0; j < 4; ++j) bf[j] = *(const float4*)&Wc[buf][tx + 32 * j][k4];
            #pragma unroll
            for (int i = 0; i < 8; ++i) {
                #pragma unroll
                for (int j = 0; j < 4; ++j) {
                    acc[i][j] += af[i].x * bf[j].x;
                    acc[i][j] += af[i].y * bf[j].y;
                    acc[i][j] += af[i].z * bf[j].z;
                    acc[i][j] += af[i].w * bf[j].w;
                }
            }
        }
        __syncthreads();
    }

    const float omb = 1.0f - b;
    #pragma unroll
    for (int i = 0; i < 8; ++i) {
        int n = nb + ty * 8 + i;
        if (n < n_nodes) {
            #pragma unroll
            for (int j = 0; j < 4; ++j) {
                int cidx = tx + 32 * j;
                float viv = vout[(size_t)n * DD + cidx];
                vout[(size_t)n * DD + cidx] = omb * viv + b * acc[i][j];
            }
        }
    }
}

// ===========================================================================
// Tier-4 fallback: atomic-scatter path
// ===========================================================================
__global__ __launch_bounds__(256) void k_scatter_edge(
    const float* __restrict__ vfeat, const int* __restrict__ node_idx,
    const int* __restrict__ edge_idx, float* __restrict__ esum,
    float* __restrict__ cnt, int nnz)
{
    int t = blockIdx.x * blockDim.x + threadIdx.x;
    int i = t >> 5;
    if (i >= nnz) return;
    int c = (t & 31) << 2;
    int n = node_idx[i];
    int e = edge_idx[i];
    const float4 v = *(const float4*)(vfeat + (size_t)n * DD + c);
    float* dst = esum + (size_t)e * DD + c;
    atomicAdd(dst + 0, v.x); atomicAdd(dst + 1, v.y);
    atomicAdd(dst + 2, v.z); atomicAdd(dst + 3, v.w);
    if ((t & 31) == 0) atomicAdd(cnt + e, 1.0f);
}

__global__ __launch_bounds__(256) void k_normalize_edge(
    float* __restrict__ efeat, const float* __restrict__ cnt, int n_edges)
{
    int t = blockIdx.x * blockDim.x + threadIdx.x;
    int e = t >> 5;
    if (e >= n_edges) return;
    int c = (t & 31) << 2;
    float inv = 1.0f / fmaxf(cnt[e], 1.0f);
    float4* p = (float4*)(efeat + (size_t)e * DD + c);
    float4 v = *p;
    v.x *= inv; v.y *= inv; v.z *= inv; v.w *= inv;
    *p = v;
}

__global__ __launch_bounds__(256) void k_scatter_node_vi(
    const float* __restrict__ efeat_new, const float* __restrict__ degE,
    const int* __restrict__ node_idx, const int* __restrict__ edge_idx,
    float* __restrict__ h, int nnz)
{
    int t = blockIdx.x * blockDim.x + threadIdx.x;
    int i = t >> 5;
    if (i >= nnz) return;
    int c = (t & 31) << 2;
    int n = node_idx[i];
    int e = edge_idx[i];
    float w = degE[e];
    const float4 v = *(const float4*)(efeat_new + (size_t)e * DD + c);
    float* dst = h + (size_t)n * DD + c;
    atomicAdd(dst + 0, w * v.x); atomicAdd(dst + 1, w * v.y);
    atomicAdd(dst + 2, w * v.z); atomicAdd(dst + 3, w * v.w);
}

__global__ __launch_bounds__(256) void k_h_to_vi(
    float* __restrict__ h, const float* __restrict__ degV,
    const float* __restrict__ vfeat0, const float* __restrict__ alpha,
    int n_nodes)
{
    int t = blockIdx.x * blockDim.x + threadIdx.x;
    int n = t >> 5;
    if (n >= n_nodes) return;
    int c = (t & 31) << 2;
    float a = alpha[0];
    float s = (1.0f - a) * degV[n];
    float4* p = (float4*)(h + (size_t)n * DD + c);
    const float4 f = *(const float4*)(vfeat0 + (size_t)n * DD + c);
    float4 v = *p;
    v.x = s * v.x + a * f.x;
    v.y = s * v.y + a * f.y;
    v.z = s * v.z + a * f.z;
    v.w = s * v.w + a * f.w;
    *p = v;
}

// ===========================================================================
extern "C" void kernel_launch(void* const* d_in, const int* in_sizes, int n_in,
                              void* d_out, int out_size, void* d_ws, size_t ws_size,
                              hipStream_t stream)
{
    const float* vfeat  = (const float*)d_in[0];
    const float* degE   = (const float*)d_in[2];
    const float* degV   = (const float*)d_in[3];
    const float* vfeat0 = (const float*)d_in[4];
    const float* W      = (const float*)d_in[5];
    const float* alpha  = (const float*)d_in[6];
    const float* beta   = (const float*)d_in[7];
    const int* node_idx = (const int*)d_in[8];
    const int* edge_idx = (const int*)d_in[9];

    const int E   = in_sizes[2];
    const int N   = in_sizes[3];
    const int NNZ = in_sizes[8];

    float* vout = (float*)d_out;
    float* eout = (float*)d_out + (size_t)N * DD;

    const int nbE = (E + 4095) / 4096;
    const int nbV = (N + 4095) / 4096;

    const int ciE = (NNZ + NCHE - 1) / NCHE;
    const int ciV = (NNZ + NCHV - 1) / NCHV;

    // tier-1 (counting sort) workspace in u32 words
    const size_t lrank_w = ((size_t)NNZ + 1) / 2;
    const size_t need_cs =
        ((size_t)E + N + (E + 1) + (N + 1) + 128
         + 2 * lrank_w
         + ((size_t)NCHE * E + 1) / 2 + ((size_t)NCHV * N + 1) / 2
         + (size_t)NCHE * E + (size_t)NCHV * N
         + 2 * (size_t)NNZ) * sizeof(int);
    const size_t need_rank = ((size_t)2 * E + 2 * N + 4 * (size_t)NNZ + 130) * sizeof(int);
    const size_t need_cur  = ((size_t)3 * E + 3 * N + 2 * (size_t)NNZ + 130) * sizeof(int);

    const bool cs_ok = (E <= 20000) && (N <= 100000) && !(E & 1) && !(N & 1)
                       && ciE <= 65535 && ciV <= 65535 && ws_size >= need_cs;

    if (cs_ok) {
        int* countE  = (int*)d_ws;                       // E
        int* countV  = countE + E;                       // N
        int* rowptrE = countV + N;                       // E+1
        int* rowptrV = rowptrE + E + 1;                  // N+1
        int* partE   = rowptrV + N + 1;                  // 64
        int* partV   = partE + 64;                       // 64
        unsigned short* lrankE = (unsigned short*)(partV + 64);       // NNZ u16
        unsigned short* lrankV = lrankE + 2 * lrank_w;                // NNZ u16
        unsigned short* histE  = lrankV + 2 * lrank_w;                // NCHE*E u16
        unsigned short* histV  = histE + 2 * (((size_t)NCHE * E + 1) / 2);
        unsigned int*   baseE  = (unsigned int*)(histV + 2 * (((size_t)NCHV * N + 1) / 2));
        unsigned int*   baseV  = baseE + (size_t)NCHE * E;
        int* adjE = (int*)(baseV + (size_t)NCHV * N);    // NNZ
        int* adjV = adjE + NNZ;                          // NNZ

        k_cnt_rank_E<<<NCHE, 1024, 0, stream>>>(edge_idx, lrankE, histE, NNZ, ciE, E);
        k_cnt_rank_V<<<dim3(NCHV, 2), 1024, 0, stream>>>(node_idx, lrankV, histV, NNZ, ciV, N);
        k_sum_prefix<<<(E + 255) / 256, 256, 0, stream>>>(histE, baseE, countE, E, NCHE);
        k_sum_prefix<<<(N + 255) / 256, 256, 0, stream>>>(histV, baseV, countV, N, NCHV);
        k_chunk_sums<<<nbE, 256, 0, stream>>>(countE, E, partE);
        k_chunk_sums<<<nbV, 256, 0, stream>>>(countV, N, partV);
        k_scan_partials2<<<2, 64, 0, stream>>>(partE, nbE, rowptrE + E,
                                               partV, nbV, rowptrV + N);
        k_scan_chunks<<<nbE, 256, 0, stream>>>(countE, E, partE, rowptrE, nullptr);
        k_scan_chunks<<<nbV, 256, 0, stream>>>(countV, N, partV, rowptrV, nullptr);

        k_fill_cs<<<2048, 256, 0, stream>>>(node_idx, edge_idx, lrankE, lrankV,
                                            baseE, baseV, rowptrE, rowptrV,
                                            adjE, adjV, NNZ, E, N, ciE, ciV);

        k_gather_edge<<<((size_t)E * 64 + 255) / 256, 256, 0, stream>>>(
            vfeat, rowptrE, adjE, eout, E);
        k_gather_node_vi<<<((size_t)N * 64 + 255) / 256, 256, 0, stream>>>(
            eout, degE, degV, vfeat0, alpha, rowptrV, adjV, vout, N);
        k_gemm_vi<<<(N + 63) / 64, 256, 0, stream>>>(vout, W, beta, N);
    } else if (ws_size >= need_rank) {
        int* countE  = (int*)d_ws;
        int* countV  = countE + E;
        int* rowptrE = countV + N;
        int* rowptrV = rowptrE + E + 1;
        int* partE   = rowptrV + N + 1;
        int* partV   = partE + 64;
        int* rankE   = partV + 64;
        int* rankV   = rankE + NNZ;
        int* adjE    = rankV + NNZ;
        int* adjV    = adjE + NNZ;

        hipMemsetAsync(countE, 0, (size_t)(E + N) * sizeof(int), stream);
        k_hist_rank<<<(NNZ + 255) / 256, 256, 0, stream>>>(
            node_idx, edge_idx, countE, countV, rankE, rankV, NNZ);
        k_chunk_sums<<<nbE, 256, 0, stream>>>(countE, E, partE);
        k_chunk_sums<<<nbV, 256, 0, stream>>>(countV, N, partV);
        k_scan_partials2<<<2, 64, 0, stream>>>(partE, nbE, rowptrE + E,
                                               partV, nbV, rowptrV + N);
        k_scan_chunks<<<nbE, 256, 0, stream>>>(countE, E, partE, rowptrE, nullptr);
        k_scan_chunks<<<nbV, 256, 0, stream>>>(countV, N, partV, rowptrV, nullptr);
        k_fill_sliced_rank<<<2048, 256, 0, stream>>>(
            node_idx, edge_idx, rankE, rankV, rowptrE, rowptrV,
            adjE, adjV, NNZ, E, N);
        k_gather_edge<<<((size_t)E * 64 + 255) / 256, 256, 0, stream>>>(
            vfeat, rowptrE, adjE, eout, E);
        k_gather_node_vi<<<((size_t)N * 64 + 255) / 256, 256, 0, stream>>>(
            eout, degE, degV, vfeat0, alpha, rowptrV, adjV, vout, N);
        k_gemm_vi<<<(N + 63) / 64, 256, 0, stream>>>(vout, W, beta, N);
    } else if (ws_size >= need_cur) {
        int* countE  = (int*)d_ws;
        int* countV  = countE + E;
        int* rowptrE = countV + N;
        int* rowptrV = rowptrE + E + 1;
        int* cursorE = rowptrV + N + 1;
        int* cursorV = cursorE + E;
        int* partE   = cursorV + N;
        int* partV   = partE + 64;
        int* adjE    = partV + 64;
        int* adjV    = adjE + NNZ;

        hipMemsetAsync(countE, 0, (size_t)(E + N) * sizeof(int), stream);
        k_hist<<<(NNZ + 255) / 256, 256, 0, stream>>>(node_idx, edge_idx,
                                                      countE, countV, NNZ);
        k_chunk_sums<<<nbE, 256, 0, stream>>>(countE, E, partE);
        k_chunk_sums<<<nbV, 256, 0, stream>>>(countV, N, partV);
        k_scan_partials2<<<2, 64, 0, stream>>>(partE, nbE, rowptrE + E,
                                               partV, nbV, rowptrV + N);
        k_scan_chunks<<<nbE, 256, 0, stream>>>(countE, E, partE, rowptrE, cursorE);
        k_scan_chunks<<<nbV, 256, 0, stream>>>(countV, N, partV, rowptrV, cursorV);
        k_fill_sliced<<<2048, 256, 0, stream>>>(node_idx, edge_idx,
                                                cursorE, cursorV,
                                                adjE, adjV, NNZ, E, N);
        k_gather_edge<<<((size_t)E * 64 + 255) / 256, 256, 0, stream>>>(
            vfeat, rowptrE, adjE, eout, E);
        k_gather_node_vi<<<((size_t)N * 64 + 255) / 256, 256, 0, stream>>>(
            eout, degE, degV, vfeat0, alpha, rowptrV, adjV, vout, N);
        k_gemm_vi<<<(N + 63) / 64, 256, 0, stream>>>(vout, W, beta, N);
    } else {
        float* cnt = (float*)d_ws;
        hipMemsetAsync(d_out, 0, (size_t)out_size * sizeof(float), stream);
        hipMemsetAsync(cnt, 0, (size_t)E * sizeof(float), stream);
        {
            long long threads = (long long)NNZ * 32;
            int blocks = (int)((threads + 255) / 256);
            k_scatter_edge<<<blocks, 256, 0, stream>>>(vfeat, node_idx, edge_idx,
                                                       eout, cnt, NNZ);
        }
        {
            int blocks = (E * 32 + 255) / 256;
            k_normalize_edge<<<blocks, 256, 0, stream>>>(eout, cnt, E);
        }
        {
            long long threads = (long long)NNZ * 32;
            int blocks = (int)((threads + 255) / 256);
            k_scatter_node_vi<<<blocks, 256, 0, stream>>>(eout, degE, node_idx, edge_idx,
                                                          vout, NNZ);
        }
        k_h_to_vi<<<((size_t)N * 32 + 255) / 256, 256, 0, stream>>>(
            vout, degV, vfeat0, alpha, N);
        k_gemm_vi<<<(N + 63) / 64, 256, 0, stream>>>(vout, W, beta, N);
    }
}

// Round 8
// 366.567 us; speedup vs baseline: 1.1610x; 1.0368x over previous
//
#include <hip/hip_runtime.h>

#define DD 128
#define NSLICE 8
#define CK 32
#define NCHE 32
#define NCHV 16

typedef unsigned int  u32;
typedef unsigned short u16;

__device__ __forceinline__ u32 bf16rne(float x) {
    u32 u = __float_as_uint(x);
    return (u + 0x7fffu + ((u >> 16) & 1u)) >> 16;
}
__device__ __forceinline__ u32 packbf2(float lo, float hi) {
    return bf16rne(lo) | (bf16rne(hi) << 16);
}
__device__ __forceinline__ float bflo(u32 r) { return __uint_as_float(r << 16); }
__device__ __forceinline__ float bfhi(u32 r) { return __uint_as_float(r & 0xffff0000u); }

// ===========================================================================
// bf16 staging: vfeat f32 -> bf16 (packed 2 per u32)
// ===========================================================================
__global__ __launch_bounds__(256) void k_to_bf16(
    const float* __restrict__ in, u32* __restrict__ out, int n_pairs)
{
    int i = blockIdx.x * blockDim.x + threadIdx.x;   // one u32 (2 floats) each
    if (i >= n_pairs) return;
    const float2 v = ((const float2*)in)[i];
    __builtin_nontemporal_store(packbf2(v.x, v.y), out + i);
}

// ===========================================================================
// Tier CSR build: LDS-privatized counting sort (zero global atomics)
// ===========================================================================
__global__ __launch_bounds__(1024) void k_cnt_rank_E(
    const int* __restrict__ idx,
    u16* __restrict__ lrank, u16* __restrict__ hist,
    int nnz, int ci, int E)
{
    __shared__ u32 lh[10000];
    const int c = blockIdx.x;
    const int tid = threadIdx.x;
    const int W = (E + 1) >> 1;
    for (int w = tid; w < W; w += 1024) lh[w] = 0u;
    __syncthreads();

    const int beg = c * ci;
    const int end = min(nnz, beg + ci);
    for (int ib = beg; ib < end; ib += 1024 * 8) {
        int v[8]; bool m[8];
        #pragma unroll
        for (int t = 0; t < 8; ++t) {
            int ii = ib + t * 1024 + tid;
            m[t] = ii < end;
            v[t] = m[t] ? __builtin_nontemporal_load(idx + ii) : 0;
        }
        #pragma unroll
        for (int t = 0; t < 8; ++t) {
            if (m[t]) {
                int s = v[t];
                unsigned sh = (s & 1) << 4;
                u32 ret = atomicAdd(&lh[s >> 1], 1u << sh);
                __builtin_nontemporal_store((u16)((ret >> sh) & 0xffffu),
                                            lrank + ib + t * 1024 + tid);
            }
        }
    }
    __syncthreads();
    u32* hp = (u32*)(hist + (size_t)c * E);
    for (int w = tid; w < W; w += 1024) hp[w] = lh[w];
}

__global__ __launch_bounds__(1024) void k_cnt_rank_V(
    const int* __restrict__ idx,
    u16* __restrict__ lrank, u16* __restrict__ hist,
    int nnz, int ci, int N)
{
    __shared__ u32 lh[25000];
    const int c = blockIdx.x;
    const int lo = blockIdx.y * 50000;
    const int hi = min(N, lo + 50000);
    const int span = hi - lo;
    const int tid = threadIdx.x;
    const int W = (span + 1) >> 1;
    for (int w = tid; w < W; w += 1024) lh[w] = 0u;
    __syncthreads();

    const int beg = c * ci;
    const int end = min(nnz, beg + ci);
    for (int ib = beg; ib < end; ib += 1024 * 8) {
        int v[8]; bool m[8];
        #pragma unroll
        for (int t = 0; t < 8; ++t) {
            int ii = ib + t * 1024 + tid;
            m[t] = ii < end;
            v[t] = m[t] ? __builtin_nontemporal_load(idx + ii) : -1;
        }
        #pragma unroll
        for (int t = 0; t < 8; ++t) {
            int s = v[t] - lo;
            if (m[t] && s >= 0 && s < span) {
                unsigned sh = (s & 1) << 4;
                u32 ret = atomicAdd(&lh[s >> 1], 1u << sh);
                __builtin_nontemporal_store((u16)((ret >> sh) & 0xffffu),
                                            lrank + ib + t * 1024 + tid);
            }
        }
    }
    __syncthreads();
    u32* hp = (u32*)(hist + (size_t)c * N + lo);
    for (int w = tid; w < W; w += 1024) hp[w] = lh[w];
}

__global__ __launch_bounds__(256) void k_sum_prefix(
    const u16* __restrict__ hist, u32* __restrict__ base,
    int* __restrict__ count, int nseg, int nchunk)
{
    int s = blockIdx.x * blockDim.x + threadIdx.x;
    if (s >= nseg) return;
    u32 run = 0;
    for (int c = 0; c < nchunk; ++c) {
        base[(size_t)c * nseg + s] = run;
        run += hist[(size_t)c * nseg + s];
    }
    count[s] = (int)run;
}

__global__ __launch_bounds__(256) void k_fill_cs(
    const int* __restrict__ node_idx,
    const int* __restrict__ edge_idx,
    const u16* __restrict__ lrankE, const u16* __restrict__ lrankV,
    const u32* __restrict__ baseE, const u32* __restrict__ baseV,
    const int* __restrict__ rowptrE, const int* __restrict__ rowptrV,
    int* __restrict__ adjE, int* __restrict__ adjV,
    int nnz, int E, int N, int ciE, int ciV)
{
    const int s = blockIdx.x & (NSLICE - 1);
    const int g = blockIdx.x >> 3;
    const int ngroups = gridDim.x >> 3;
    const int eb = (E + NSLICE - 1) / NSLICE;
    const int nb = (N + NSLICE - 1) / NSLICE;
    const int elo = s * eb, ehi = min(E, elo + eb);
    const int nlo = s * nb, nhi = min(N, nlo + nb);

    const int stride = ngroups * 256;
    for (int i = g * 256 + threadIdx.x; i < nnz; i += stride) {
        int n = __builtin_nontemporal_load(node_idx + i);
        int e = __builtin_nontemporal_load(edge_idx + i);
        if (e >= elo && e < ehi) {
            int ce = (int)((unsigned)i / (unsigned)ciE);
            int p = rowptrE[e] + (int)baseE[(size_t)ce * E + e]
                  + (int)__builtin_nontemporal_load(lrankE + i);
            __builtin_nontemporal_store(n, adjE + p);
        }
        if (n >= nlo && n < nhi) {
            int cv = (int)((unsigned)i / (unsigned)ciV);
            int p = rowptrV[n] + (int)baseV[(size_t)cv * N + n]
                  + (int)__builtin_nontemporal_load(lrankV + i);
            __builtin_nontemporal_store(e, adjV + p);
        }
    }
}

// ===========================================================================
// Shared scan infrastructure
// ===========================================================================
__global__ __launch_bounds__(256) void k_chunk_sums(
    const int* __restrict__ cnt, int L, int* __restrict__ partials)
{
    __shared__ int red[256];
    const int tid = threadIdx.x;
    const int base = blockIdx.x * 4096;
    int s = 0;
    for (int j = tid; j < 4096; j += 256) {
        int i = base + j;
        s += (i < L) ? cnt[i] : 0;
    }
    red[tid] = s;
    __syncthreads();
    for (int off = 128; off > 0; off >>= 1) {
        if (tid < off) red[tid] += red[tid + off];
        __syncthreads();
    }
    if (tid == 0) partials[blockIdx.x] = red[0];
}

__global__ void k_scan_partials2(int* __restrict__ pE, int nbE, int* __restrict__ totE,
                                 int* __restrict__ pV, int nbV, int* __restrict__ totV)
{
    if (threadIdx.x != 0) return;
    int* p = (blockIdx.x == 0) ? pE : pV;
    int  nb = (blockIdx.x == 0) ? nbE : nbV;
    int* tot = (blockIdx.x == 0) ? totE : totV;
    int run = 0;
    for (int b = 0; b < nb; ++b) {
        int t = p[b];
        p[b] = run;
        run += t;
    }
    *tot = run;
}

__global__ __launch_bounds__(256) void k_scan_chunks(
    const int* __restrict__ cnt, int L,
    const int* __restrict__ partials,
    int* __restrict__ rowptr, int* __restrict__ cursor)
{
    __shared__ int tsum[256];
    const int tid = threadIdx.x;
    const int tbase = blockIdx.x * 4096 + tid * 16;
    int loc[16];
    int s = 0;
    #pragma unroll
    for (int k = 0; k < 16; ++k) {
        int i = tbase + k;
        loc[k] = (i < L) ? cnt[i] : 0;
        s += loc[k];
    }
    tsum[tid] = s;
    __syncthreads();
    if (tid == 0) {
        int run = partials[blockIdx.x];
        for (int j = 0; j < 256; ++j) {
            int t = tsum[j];
            tsum[j] = run;
            run += t;
        }
    }
    __syncthreads();
    int run = tsum[tid];
    #pragma unroll
    for (int k = 0; k < 16; ++k) {
        int i = tbase + k;
        if (i < L) {
            rowptr[i] = run;
            if (cursor) cursor[i] = run;
        }
        run += loc[k];
    }
}

// ===========================================================================
// bf16 gather stages (tier-0): wave64 per row, one packed u32 (2 cols) / lane
// ===========================================================================

// stage 1: efeat_new[e] = mean of bf16 vfeat rows; writes f32 efeat (output)
// and bf16 pre-scaled copy efsc[e] = degE[e] * efeat_new[e] for stage 2.
__global__ __launch_bounds__(256) void k_gather_edge_bf(
    const u32* __restrict__ vfeat_bf,      // [N][64] packed
    const float* __restrict__ degE,
    const int* __restrict__ rowptrE,
    const int* __restrict__ adjE,
    float* __restrict__ efeat,             // [E][128] f32 out
    u32* __restrict__ efsc,                // [E][64] packed bf16 out
    int n_edges)
{
    const int row = (blockIdx.x * blockDim.x + threadIdx.x) >> 6;
    if (row >= n_edges) return;
    const int lane = threadIdx.x & 63;
    const int beg = rowptrE[row];
    const int len = rowptrE[row + 1] - beg;

    const u32* vb = vfeat_bf + lane;
    float2 c0 = {0,0}, c1 = {0,0}, c2 = {0,0}, c3 = {0,0};
    float2 c4 = {0,0}, c5 = {0,0}, c6 = {0,0}, c7 = {0,0};

    int k = 0;
    for (; k + 8 <= len; k += 8) {
        int e0 = adjE[beg + k + 0]; int e1 = adjE[beg + k + 1];
        int e2 = adjE[beg + k + 2]; int e3 = adjE[beg + k + 3];
        int e4 = adjE[beg + k + 4]; int e5 = adjE[beg + k + 5];
        int e6 = adjE[beg + k + 6]; int e7 = adjE[beg + k + 7];
        u32 r0 = vb[(size_t)e0 * 64]; u32 r1 = vb[(size_t)e1 * 64];
        u32 r2 = vb[(size_t)e2 * 64]; u32 r3 = vb[(size_t)e3 * 64];
        u32 r4 = vb[(size_t)e4 * 64]; u32 r5 = vb[(size_t)e5 * 64];
        u32 r6 = vb[(size_t)e6 * 64]; u32 r7 = vb[(size_t)e7 * 64];
        c0.x += bflo(r0); c0.y += bfhi(r0);
        c1.x += bflo(r1); c1.y += bfhi(r1);
        c2.x += bflo(r2); c2.y += bfhi(r2);
        c3.x += bflo(r3); c3.y += bfhi(r3);
        c4.x += bflo(r4); c4.y += bfhi(r4);
        c5.x += bflo(r5); c5.y += bfhi(r5);
        c6.x += bflo(r6); c6.y += bfhi(r6);
        c7.x += bflo(r7); c7.y += bfhi(r7);
    }
    for (; k < len; ++k) {
        u32 r0 = vb[(size_t)adjE[beg + k] * 64];
        c0.x += bflo(r0); c0.y += bfhi(r0);
    }
    float inv = (len > 0) ? 1.0f / (float)len : 0.0f;
    float2 o;
    o.x = (c0.x + c1.x + c2.x + c3.x + c4.x + c5.x + c6.x + c7.x) * inv;
    o.y = (c0.y + c1.y + c2.y + c3.y + c4.y + c5.y + c6.y + c7.y) * inv;
    ((float2*)(efeat + (size_t)row * DD))[lane] = o;
    const float dE = degE[row];
    __builtin_nontemporal_store(packbf2(o.x * dE, o.y * dE),
                                efsc + (size_t)row * 64 + lane);
}

// stage 2: vi[n] = (1-a)*degV[n]*sum(efsc[e]) + a*vfeat0[n]
__global__ __launch_bounds__(256) void k_gather_node_vi_bf(
    const u32* __restrict__ efsc,          // [E][64] packed (degE pre-folded)
    const float* __restrict__ degV,
    const float* __restrict__ vfeat0,
    const float* __restrict__ alpha,
    const int* __restrict__ rowptrV,
    const int* __restrict__ adjV,
    float* __restrict__ vi,
    int n_nodes)
{
    const int row = (blockIdx.x * blockDim.x + threadIdx.x) >> 6;
    if (row >= n_nodes) return;
    const int lane = threadIdx.x & 63;
    const int beg = rowptrV[row];
    const int len = rowptrV[row + 1] - beg;

    const u32* eb = efsc + lane;
    float2 c0 = {0,0}, c1 = {0,0}, c2 = {0,0}, c3 = {0,0};
    float2 c4 = {0,0}, c5 = {0,0}, c6 = {0,0}, c7 = {0,0};

    int k = 0;
    for (; k + 8 <= len; k += 8) {
        int e0 = adjV[beg + k + 0]; int e1 = adjV[beg + k + 1];
        int e2 = adjV[beg + k + 2]; int e3 = adjV[beg + k + 3];
        int e4 = adjV[beg + k + 4]; int e5 = adjV[beg + k + 5];
        int e6 = adjV[beg + k + 6]; int e7 = adjV[beg + k + 7];
        u32 r0 = eb[(size_t)e0 * 64]; u32 r1 = eb[(size_t)e1 * 64];
        u32 r2 = eb[(size_t)e2 * 64]; u32 r3 = eb[(size_t)e3 * 64];
        u32 r4 = eb[(size_t)e4 * 64]; u32 r5 = eb[(size_t)e5 * 64];
        u32 r6 = eb[(size_t)e6 * 64]; u32 r7 = eb[(size_t)e7 * 64];
        c0.x += bflo(r0); c0.y += bfhi(r0);
        c1.x += bflo(r1); c1.y += bfhi(r1);
        c2.x += bflo(r2); c2.y += bfhi(r2);
        c3.x += bflo(r3); c3.y += bfhi(r3);
        c4.x += bflo(r4); c4.y += bfhi(r4);
        c5.x += bflo(r5); c5.y += bfhi(r5);
        c6.x += bflo(r6); c6.y += bfhi(r6);
        c7.x += bflo(r7); c7.y += bfhi(r7);
    }
    for (; k < len; ++k) {
        u32 r0 = eb[(size_t)adjV[beg + k] * 64];
        c0.x += bflo(r0); c0.y += bfhi(r0);
    }
    const float a = alpha[0];
    const float s = (1.0f - a) * degV[row];
    const float2 f = ((const float2*)(vfeat0 + (size_t)row * DD))[lane];
    float2 o;
    o.x = s * (c0.x + c1.x + c2.x + c3.x + c4.x + c5.x + c6.x + c7.x) + a * f.x;
    o.y = s * (c0.y + c1.y + c2.y + c3.y + c4.y + c5.y + c6.y + c7.y) + a * f.y;
    ((float2*)(vi + (size_t)row * DD))[lane] = o;
}

// ===========================================================================
// f32 gather stages (tier-1 fallback)
// ===========================================================================
__global__ __launch_bounds__(256) void k_gather_edge(
    const float* __restrict__ vfeat,
    const int* __restrict__ rowptrE,
    const int* __restrict__ adjE,
    float* __restrict__ efeat,
    int n_edges)
{
    const int row = (blockIdx.x * blockDim.x + threadIdx.x) >> 6;
    if (row >= n_edges) return;
    const int lane = threadIdx.x & 63;
    const int beg = rowptrE[row];
    const int len = rowptrE[row + 1] - beg;

    const float2* vb = (const float2*)vfeat + lane;
    float2 c0 = {0,0}, c1 = {0,0}, c2 = {0,0}, c3 = {0,0};
    int k = 0;
    for (; k + 4 <= len; k += 4) {
        int e0 = adjE[beg + k + 0]; int e1 = adjE[beg + k + 1];
        int e2 = adjE[beg + k + 2]; int e3 = adjE[beg + k + 3];
        float2 r0 = vb[(size_t)e0 * 64]; float2 r1 = vb[(size_t)e1 * 64];
        float2 r2 = vb[(size_t)e2 * 64]; float2 r3 = vb[(size_t)e3 * 64];
        c0.x += r0.x; c0.y += r0.y; c1.x += r1.x; c1.y += r1.y;
        c2.x += r2.x; c2.y += r2.y; c3.x += r3.x; c3.y += r3.y;
    }
    for (; k < len; ++k) {
        float2 r0 = vb[(size_t)adjE[beg + k] * 64];
        c0.x += r0.x; c0.y += r0.y;
    }
    float inv = (len > 0) ? 1.0f / (float)len : 0.0f;
    float2 o;
    o.x = (c0.x + c1.x + c2.x + c3.x) * inv;
    o.y = (c0.y + c1.y + c2.y + c3.y) * inv;
    ((float2*)(efeat + (size_t)row * DD))[lane] = o;
}

__global__ __launch_bounds__(256) void k_gather_node_vi(
    const float* __restrict__ efeat,
    const float* __restrict__ degE,
    const float* __restrict__ degV,
    const float* __restrict__ vfeat0,
    const float* __restrict__ alpha,
    const int* __restrict__ rowptrV,
    const int* __restrict__ adjV,
    float* __restrict__ vi,
    int n_nodes)
{
    const int row = (blockIdx.x * blockDim.x + threadIdx.x) >> 6;
    if (row >= n_nodes) return;
    const int lane = threadIdx.x & 63;
    const int beg = rowptrV[row];
    const int len = rowptrV[row + 1] - beg;

    const float2* eb = (const float2*)efeat + lane;
    float2 c0 = {0,0}, c1 = {0,0}, c2 = {0,0}, c3 = {0,0};
    int k = 0;
    for (; k + 4 <= len; k += 4) {
        int e0 = adjV[beg + k + 0]; int e1 = adjV[beg + k + 1];
        int e2 = adjV[beg + k + 2]; int e3 = adjV[beg + k + 3];
        float w0 = degE[e0], w1 = degE[e1], w2 = degE[e2], w3 = degE[e3];
        float2 r0 = eb[(size_t)e0 * 64]; float2 r1 = eb[(size_t)e1 * 64];
        float2 r2 = eb[(size_t)e2 * 64]; float2 r3 = eb[(size_t)e3 * 64];
        c0.x += w0 * r0.x; c0.y += w0 * r0.y;
        c1.x += w1 * r1.x; c1.y += w1 * r1.y;
        c2.x += w2 * r2.x; c2.y += w2 * r2.y;
        c3.x += w3 * r3.x; c3.y += w3 * r3.y;
    }
    for (; k < len; ++k) {
        int e0 = adjV[beg + k];
        float w0 = degE[e0];
        float2 r0 = eb[(size_t)e0 * 64];
        c0.x += w0 * r0.x; c0.y += w0 * r0.y;
    }
    const float a = alpha[0];
    const float s = (1.0f - a) * degV[row];
    const float2 f = ((const float2*)(vfeat0 + (size_t)row * DD))[lane];
    float2 o;
    o.x = s * (c0.x + c1.x + c2.x + c3.x) + a * f.x;
    o.y = s * (c0.y + c1.y + c2.y + c3.y) + a * f.y;
    ((float2*)(vi + (size_t)row * DD))[lane] = o;
}

// ---------------------------------------------------------------------------
// K-chunked, double-buffered epilogue GEMM, in place on vout (vi -> v).
// ---------------------------------------------------------------------------
__global__ __launch_bounds__(256) void k_gemm_vi(
    float* __restrict__ vout,
    const float* __restrict__ W,
    const float* __restrict__ beta,
    int n_nodes)
{
    __shared__ float Wc[2][128][CK + 4];
    __shared__ float Ac[2][64][CK];

    const int tid = threadIdx.x;
    const float b = beta[0];
    const int nb = blockIdx.x * 64;
    const int tx = tid & 31;
    const int ty = tid >> 5;

    float acc[8][4];
    #pragma unroll
    for (int i = 0; i < 8; ++i)
        #pragma unroll
        for (int j = 0; j < 4; ++j) acc[i][j] = 0.0f;

    auto stage = [&](int chunk, int buf) {
        const int kb = chunk * CK;
        #pragma unroll
        for (int p = 0; p < 4; ++p) {
            int idx = tid + p * 256;
            int row = idx >> 3;
            int l4 = (idx & 7) << 2;
            *(float4*)&Wc[buf][row][l4] = *(const float4*)(W + row * DD + kb + l4);
        }
        #pragma unroll
        for (int p = 0; p < 2; ++p) {
            int idx = tid + p * 256;
            int row = idx >> 3;
            int l4 = (idx & 7) << 2;
            int n = nb + row;
            float4 v = {0, 0, 0, 0};
            if (n < n_nodes) v = *(const float4*)(vout + (size_t)n * DD + kb + l4);
            *(float4*)&Ac[buf][row][l4] = v;
        }
    };

    stage(0, 0);
    __syncthreads();

    const int NCHUNK = DD / CK;
    for (int c = 0; c < NCHUNK; ++c) {
        if (c + 1 < NCHUNK) stage(c + 1, (c + 1) & 1);
        const int buf = c & 1;
        #pragma unroll
        for (int kc = 0; kc < CK / 4; ++kc) {
            const int k4 = kc << 2;
            float4 af[8];
            #pragma unroll
            for (int i = 0; i < 8; ++i) af[i] = *(const float4*)&Ac[buf][ty * 8 + i][k4];
            float4 bf[4];
            #pragma unroll
            for (int j = 0; j < 4; ++j) bf[j] = *(const float4*)&Wc[buf][tx + 32 * j][k4];
            #pragma unroll
            for (int i = 0; i < 8; ++i) {
                #pragma unroll
                for (int j = 0; j < 4; ++j) {
                    acc[i][j] += af[i].x * bf[j].x;
                    acc[i][j] += af[i].y * bf[j].y;
                    acc[i][j] += af[i].z * bf[j].z;
                    acc[i][j] += af[i].w * bf[j].w;
                }
            }
        }
        __syncthreads();
    }

    const float omb = 1.0f - b;
    #pragma unroll
    for (int i = 0; i < 8; ++i) {
        int n = nb + ty * 8 + i;
        if (n < n_nodes) {
            #pragma unroll
            for (int j = 0; j < 4; ++j) {
                int cidx = tx + 32 * j;
                float viv = vout[(size_t)n * DD + cidx];
                vout[(size_t)n * DD + cidx] = omb * viv + b * acc[i][j];
            }
        }
    }
}

// ===========================================================================
// Deep-fallback kernels (rank path / atomic scatter)
// ===========================================================================
__global__ __launch_bounds__(256) void k_hist_rank(
    const int* __restrict__ node_idx, const int* __restrict__ edge_idx,
    int* __restrict__ countE, int* __restrict__ countV,
    int* __restrict__ rankE, int* __restrict__ rankV, int nnz)
{
    int i = blockIdx.x * blockDim.x + threadIdx.x;
    if (i >= nnz) return;
    int e = __builtin_nontemporal_load(edge_idx + i);
    int n = __builtin_nontemporal_load(node_idx + i);
    int re = atomicAdd(&countE[e], 1);
    int rv = atomicAdd(&countV[n], 1);
    __builtin_nontemporal_store(re, rankE + i);
    __builtin_nontemporal_store(rv, rankV + i);
}

__global__ __launch_bounds__(256) void k_fill_sliced_rank(
    const int* __restrict__ node_idx, const int* __restrict__ edge_idx,
    const int* __restrict__ rankE, const int* __restrict__ rankV,
    const int* __restrict__ rowptrE, const int* __restrict__ rowptrV,
    int* __restrict__ adjE, int* __restrict__ adjV,
    int nnz, int E, int N)
{
    const int s = blockIdx.x & (NSLICE - 1);
    const int g = blockIdx.x >> 3;
    const int ngroups = gridDim.x >> 3;
    const int eb = (E + NSLICE - 1) / NSLICE;
    const int nb = (N + NSLICE - 1) / NSLICE;
    const int elo = s * eb, ehi = min(E, elo + eb);
    const int nlo = s * nb, nhi = min(N, nlo + nb);
    const int stride = ngroups * 256;
    for (int i = g * 256 + threadIdx.x; i < nnz; i += stride) {
        int n = __builtin_nontemporal_load(node_idx + i);
        int e = __builtin_nontemporal_load(edge_idx + i);
        if (e >= elo && e < ehi) {
            int p = rowptrE[e] + __builtin_nontemporal_load(rankE + i);
            __builtin_nontemporal_store(n, adjE + p);
        }
        if (n >= nlo && n < nhi) {
            int p = rowptrV[n] + __builtin_nontemporal_load(rankV + i);
            __builtin_nontemporal_store(e, adjV + p);
        }
    }
}

__global__ __launch_bounds__(256) void k_scatter_edge(
    const float* __restrict__ vfeat, const int* __restrict__ node_idx,
    const int* __restrict__ edge_idx, float* __restrict__ esum,
    float* __restrict__ cnt, int nnz)
{
    int t = blockIdx.x * blockDim.x + threadIdx.x;
    int i = t >> 5;
    if (i >= nnz) return;
    int c = (t & 31) << 2;
    int n = node_idx[i];
    int e = edge_idx[i];
    const float4 v = *(const float4*)(vfeat + (size_t)n * DD + c);
    float* dst = esum + (size_t)e * DD + c;
    atomicAdd(dst + 0, v.x); atomicAdd(dst + 1, v.y);
    atomicAdd(dst + 2, v.z); atomicAdd(dst + 3, v.w);
    if ((t & 31) == 0) atomicAdd(cnt + e, 1.0f);
}

__global__ __launch_bounds__(256) void k_normalize_edge(
    float* __restrict__ efeat, const float* __restrict__ cnt, int n_edges)
{
    int t = blockIdx.x * blockDim.x + threadIdx.x;
    int e = t >> 5;
    if (e >= n_edges) return;
    int c = (t & 31) << 2;
    float inv = 1.0f / fmaxf(cnt[e], 1.0f);
    float4* p = (float4*)(efeat + (size_t)e * DD + c);
    float4 v = *p;
    v.x *= inv; v.y *= inv; v.z *= inv; v.w *= inv;
    *p = v;
}

__global__ __launch_bounds__(256) void k_scatter_node_vi(
    const float* __restrict__ efeat_new, const float* __restrict__ degE,
    const int* __restrict__ node_idx, const int* __restrict__ edge_idx,
    float* __restrict__ h, int nnz)
{
    int t = blockIdx.x * blockDim.x + threadIdx.x;
    int i = t >> 5;
    if (i >= nnz) return;
    int c = (t & 31) << 2;
    int n = node_idx[i];
    int e = edge_idx[i];
    float w = degE[e];
    const float4 v = *(const float4*)(efeat_new + (size_t)e * DD + c);
    float* dst = h + (size_t)n * DD + c;
    atomicAdd(dst + 0, w * v.x); atomicAdd(dst + 1, w * v.y);
    atomicAdd(dst + 2, w * v.z); atomicAdd(dst + 3, w * v.w);
}

__global__ __launch_bounds__(256) void k_h_to_vi(
    float* __restrict__ h, const float* __restrict__ degV,
    const float* __restrict__ vfeat0, const float* __restrict__ alpha,
    int n_nodes)
{
    int t = blockIdx.x * blockDim.x + threadIdx.x;
    int n = t >> 5;
    if (n >= n_nodes) return;
    int c = (t & 31) << 2;
    float a = alpha[0];
    float s = (1.0f - a) * degV[n];
    float4* p = (float4*)(h + (size_t)n * DD + c);
    const float4 f = *(const float4*)(vfeat0 + (size_t)n * DD + c);
    float4 v = *p;
    v.x = s * v.x + a * f.x;
    v.y = s * v.y + a * f.y;
    v.z = s * v.z + a * f.z;
    v.w = s * v.w + a * f.w;
    *p = v;
}

// ===========================================================================
extern "C" void kernel_launch(void* const* d_in, const int* in_sizes, int n_in,
                              void* d_out, int out_size, void* d_ws, size_t ws_size,
                              hipStream_t stream)
{
    const float* vfeat  = (const float*)d_in[0];
    const float* degE   = (const float*)d_in[2];
    const float* degV   = (const float*)d_in[3];
    const float* vfeat0 = (const float*)d_in[4];
    const float* W      = (const float*)d_in[5];
    const float* alpha  = (const float*)d_in[6];
    const float* beta   = (const float*)d_in[7];
    const int* node_idx = (const int*)d_in[8];
    const int* edge_idx = (const int*)d_in[9];

    const int E   = in_sizes[2];
    const int N   = in_sizes[3];
    const int NNZ = in_sizes[8];

    float* vout = (float*)d_out;
    float* eout = (float*)d_out + (size_t)N * DD;

    const int nbE = (E + 4095) / 4096;
    const int nbV = (N + 4095) / 4096;
    const int ciE = (NNZ + NCHE - 1) / NCHE;
    const int ciV = (NNZ + NCHV - 1) / NCHV;

    const size_t lrank_w = ((size_t)NNZ + 1) / 2;
    const size_t cs_words =
        (size_t)E + N + (E + 1) + (N + 1) + 128
        + 2 * lrank_w
        + ((size_t)NCHE * E + 1) / 2 + ((size_t)NCHV * N + 1) / 2
        + (size_t)NCHE * E + (size_t)NCHV * N
        + 2 * (size_t)NNZ;
    const size_t need_cs = cs_words * sizeof(int);
    const size_t bf_words = ((size_t)N * 64) + ((size_t)E * 64);  // packed u32
    const size_t need_bf = (cs_words + bf_words) * sizeof(int);
    const size_t need_rank = ((size_t)2 * E + 2 * N + 4 * (size_t)NNZ + 130) * sizeof(int);

    const bool cs_shape_ok = (E <= 20000) && (N <= 100000) && !(E & 1) && !(N & 1)
                             && ciE <= 65535 && ciV <= 65535 && !(DD & 1);

    if (cs_shape_ok && ws_size >= need_cs) {
        int* countE  = (int*)d_ws;
        int* countV  = countE + E;
        int* rowptrE = countV + N;
        int* rowptrV = rowptrE + E + 1;
        int* partE   = rowptrV + N + 1;
        int* partV   = partE + 64;
        u16* lrankE = (u16*)(partV + 64);
        u16* lrankV = lrankE + 2 * lrank_w;
        u16* histE  = lrankV + 2 * lrank_w;
        u16* histV  = histE + 2 * (((size_t)NCHE * E + 1) / 2);
        u32* baseE  = (u32*)(histV + 2 * (((size_t)NCHV * N + 1) / 2));
        u32* baseV  = baseE + (size_t)NCHE * E;
        int* adjE = (int*)(baseV + (size_t)NCHV * N);
        int* adjV = adjE + NNZ;
        u32* vfeat_bf = (u32*)(adjV + NNZ);          // N*64 (tier-0 only)
        u32* efsc_bf  = vfeat_bf + (size_t)N * 64;   // E*64 (tier-0 only)

        const bool bf_ok = ws_size >= need_bf;

        if (bf_ok) {
            int npairs = N * 64;
            k_to_bf16<<<(npairs + 255) / 256, 256, 0, stream>>>(vfeat, vfeat_bf, npairs);
        }
        k_cnt_rank_E<<<NCHE, 1024, 0, stream>>>(edge_idx, lrankE, histE, NNZ, ciE, E);
        k_cnt_rank_V<<<dim3(NCHV, 2), 1024, 0, stream>>>(node_idx, lrankV, histV, NNZ, ciV, N);
        k_sum_prefix<<<(E + 255) / 256, 256, 0, stream>>>(histE, baseE, countE, E, NCHE);
        k_sum_prefix<<<(N + 255) / 256, 256, 0, stream>>>(histV, baseV, countV, N, NCHV);
        k_chunk_sums<<<nbE, 256, 0, stream>>>(countE, E, partE);
        k_chunk_sums<<<nbV, 256, 0, stream>>>(countV, N, partV);
        k_scan_partials2<<<2, 64, 0, stream>>>(partE, nbE, rowptrE + E,
                                               partV, nbV, rowptrV + N);
        k_scan_chunks<<<nbE, 256, 0, stream>>>(countE, E, partE, rowptrE, nullptr);
        k_scan_chunks<<<nbV, 256, 0, stream>>>(countV, N, partV, rowptrV, nullptr);

        k_fill_cs<<<2048, 256, 0, stream>>>(node_idx, edge_idx, lrankE, lrankV,
                                            baseE, baseV, rowptrE, rowptrV,
                                            adjE, adjV, NNZ, E, N, ciE, ciV);

        if (bf_ok) {
            k_gather_edge_bf<<<((size_t)E * 64 + 255) / 256, 256, 0, stream>>>(
                vfeat_bf, degE, rowptrE, adjE, eout, efsc_bf, E);
            k_gather_node_vi_bf<<<((size_t)N * 64 + 255) / 256, 256, 0, stream>>>(
                efsc_bf, degV, vfeat0, alpha, rowptrV, adjV, vout, N);
        } else {
            k_gather_edge<<<((size_t)E * 64 + 255) / 256, 256, 0, stream>>>(
                vfeat, rowptrE, adjE, eout, E);
            k_gather_node_vi<<<((size_t)N * 64 + 255) / 256, 256, 0, stream>>>(
                eout, degE, degV, vfeat0, alpha, rowptrV, adjV, vout, N);
        }
        k_gemm_vi<<<(N + 63) / 64, 256, 0, stream>>>(vout, W, beta, N);
    } else if (ws_size >= need_rank) {
        int* countE  = (int*)d_ws;
        int* countV  = countE + E;
        int* rowptrE = countV + N;
        int* rowptrV = rowptrE + E + 1;
        int* partE   = rowptrV + N + 1;
        int* partV   = partE + 64;
        int* rankE   = partV + 64;
        int* rankV   = rankE + NNZ;
        int* adjE    = rankV + NNZ;
        int* adjV    = adjE + NNZ;

        hipMemsetAsync(countE, 0, (size_t)(E + N) * sizeof(int), stream);
        k_hist_rank<<<(NNZ + 255) / 256, 256, 0, stream>>>(
            node_idx, edge_idx, countE, countV, rankE, rankV, NNZ);
        k_chunk_sums<<<nbE, 256, 0, stream>>>(countE, E, partE);
        k_chunk_sums<<<nbV, 256, 0, stream>>>(countV, N, partV);
        k_scan_partials2<<<2, 64, 0, stream>>>(partE, nbE, rowptrE + E,
                                               partV, nbV, rowptrV + N);
        k_scan_chunks<<<nbE, 256, 0, stream>>>(countE, E, partE, rowptrE, nullptr);
        k_scan_chunks<<<nbV, 256, 0, stream>>>(countV, N, partV, rowptrV, nullptr);
        k_fill_sliced_rank<<<2048, 256, 0, stream>>>(
            node_idx, edge_idx, rankE, rankV, rowptrE, rowptrV,
            adjE, adjV, NNZ, E, N);
        k_gather_edge<<<((size_t)E * 64 + 255) / 256, 256, 0, stream>>>(
            vfeat, rowptrE, adjE, eout, E);
        k_gather_node_vi<<<((size_t)N * 64 + 255) / 256, 256, 0, stream>>>(
            eout, degE, degV, vfeat0, alpha, rowptrV, adjV, vout, N);
        k_gemm_vi<<<(N + 63) / 64, 256, 0, stream>>>(vout, W, beta, N);
    } else {
        float* cnt = (float*)d_ws;
        hipMemsetAsync(d_out, 0, (size_t)out_size * sizeof(float), stream);
        hipMemsetAsync(cnt, 0, (size_t)E * sizeof(float), stream);
        {
            long long threads = (long long)NNZ * 32;
            int blocks = (int)((threads + 255) / 256);
            k_scatter_edge<<<blocks, 256, 0, stream>>>(vfeat, node_idx, edge_idx,
                                                       eout, cnt, NNZ);
        }
        {
            int blocks = (E * 32 + 255) / 256;
            k_normalize_edge<<<blocks, 256, 0, stream>>>(eout, cnt, E);
        }
        {
            long long threads = (long long)NNZ * 32;
            int blocks = (int)((threads + 255) / 256);
            k_scatter_node_vi<<<blocks, 256, 0, stream>>>(eout, degE, node_idx, edge_idx,
                                                          vout, NNZ);
        }
        k_h_to_vi<<<((size_t)N * 32 + 255) / 256, 256, 0, stream>>>(
            vout, degV, vfeat0, alpha, N);
        k_gemm_vi<<<(N + 63) / 64, 256, 0, stream>>>(vout, W, beta, N);
    }
}

// Round 9
// 331.534 us; speedup vs baseline: 1.2836x; 1.1057x over previous
//
#include <hip/hip_runtime.h>

#define DD 128
#define NSLICE 8
#define CK 32
#define NCHE 32
#define NCHV 16

typedef unsigned int  u32;
typedef unsigned short u16;

__device__ __forceinline__ u32 bf16rne(float x) {
    u32 u = __float_as_uint(x);
    return (u + 0x7fffu + ((u >> 16) & 1u)) >> 16;
}
__device__ __forceinline__ u32 packbf2(float lo, float hi) {
    return bf16rne(lo) | (bf16rne(hi) << 16);
}
__device__ __forceinline__ float bflo(u32 r) { return __uint_as_float(r << 16); }
__device__ __forceinline__ float bfhi(u32 r) { return __uint_as_float(r & 0xffff0000u); }

// ===========================================================================
// bf16 staging: vfeat f32 -> bf16 (packed 2 per u32)
// ===========================================================================
__global__ __launch_bounds__(256) void k_to_bf16(
    const float* __restrict__ in, u32* __restrict__ out, int n_pairs)
{
    int i = blockIdx.x * blockDim.x + threadIdx.x;
    if (i >= n_pairs) return;
    const float2 v = ((const float2*)in)[i];
    __builtin_nontemporal_store(packbf2(v.x, v.y), out + i);
}

// ===========================================================================
// Tier-0 CSR build: LDS-privatized counting sort (zero global atomics)
// ===========================================================================
__global__ __launch_bounds__(1024) void k_cnt_rank_E(
    const int* __restrict__ idx,
    u16* __restrict__ lrank, u16* __restrict__ hist,
    int nnz, int ci, int E)
{
    __shared__ u32 lh[10000];
    const int c = blockIdx.x;
    const int tid = threadIdx.x;
    const int W = (E + 1) >> 1;
    for (int w = tid; w < W; w += 1024) lh[w] = 0u;
    __syncthreads();

    const int beg = c * ci;
    const int end = min(nnz, beg + ci);
    for (int ib = beg; ib < end; ib += 1024 * 8) {
        int v[8]; bool m[8];
        #pragma unroll
        for (int t = 0; t < 8; ++t) {
            int ii = ib + t * 1024 + tid;
            m[t] = ii < end;
            v[t] = m[t] ? __builtin_nontemporal_load(idx + ii) : 0;
        }
        #pragma unroll
        for (int t = 0; t < 8; ++t) {
            if (m[t]) {
                int s = v[t];
                unsigned sh = (s & 1) << 4;
                u32 ret = atomicAdd(&lh[s >> 1], 1u << sh);
                __builtin_nontemporal_store((u16)((ret >> sh) & 0xffffu),
                                            lrank + ib + t * 1024 + tid);
            }
        }
    }
    __syncthreads();
    u32* hp = (u32*)(hist + (size_t)c * E);
    for (int w = tid; w < W; w += 1024) hp[w] = lh[w];
}

__global__ __launch_bounds__(1024) void k_cnt_rank_V(
    const int* __restrict__ idx,
    u16* __restrict__ lrank, u16* __restrict__ hist,
    int nnz, int ci, int N)
{
    __shared__ u32 lh[25000];
    const int c = blockIdx.x;
    const int lo = blockIdx.y * 50000;
    const int hi = min(N, lo + 50000);
    const int span = hi - lo;
    const int tid = threadIdx.x;
    const int W = (span + 1) >> 1;
    for (int w = tid; w < W; w += 1024) lh[w] = 0u;
    __syncthreads();

    const int beg = c * ci;
    const int end = min(nnz, beg + ci);
    for (int ib = beg; ib < end; ib += 1024 * 8) {
        int v[8]; bool m[8];
        #pragma unroll
        for (int t = 0; t < 8; ++t) {
            int ii = ib + t * 1024 + tid;
            m[t] = ii < end;
            v[t] = m[t] ? __builtin_nontemporal_load(idx + ii) : -1;
        }
        #pragma unroll
        for (int t = 0; t < 8; ++t) {
            int s = v[t] - lo;
            if (m[t] && s >= 0 && s < span) {
                unsigned sh = (s & 1) << 4;
                u32 ret = atomicAdd(&lh[s >> 1], 1u << sh);
                __builtin_nontemporal_store((u16)((ret >> sh) & 0xffffu),
                                            lrank + ib + t * 1024 + tid);
            }
        }
    }
    __syncthreads();
    u32* hp = (u32*)(hist + (size_t)c * N + lo);
    for (int w = tid; w < W; w += 1024) hp[w] = lh[w];
}

__global__ __launch_bounds__(256) void k_sum_prefix(
    const u16* __restrict__ hist, u32* __restrict__ base,
    int* __restrict__ count, int nseg, int nchunk)
{
    int s = blockIdx.x * blockDim.x + threadIdx.x;
    if (s >= nseg) return;
    u32 run = 0;
    for (int c = 0; c < nchunk; ++c) {
        base[(size_t)c * nseg + s] = run;
        run += hist[(size_t)c * nseg + s];
    }
    count[s] = (int)run;
}

// fold rowptr into base: base'[c][s] = base[c][s] + rowptr[s]
__global__ __launch_bounds__(256) void k_add_rowptr(
    u32* __restrict__ base, const int* __restrict__ rowptr, int nseg)
{
    int s = blockIdx.x * blockDim.x + threadIdx.x;
    if (s >= nseg) return;
    base[(size_t)blockIdx.y * nseg + s] += (u32)rowptr[s];
}

// ---- XCD-sliced, atomic-free fill; ONE random table load per side --------
// adj stores are PLAIN (cached): the slice's dirty window lives in one XCD's
// L2 and coalesces to full-line writebacks. Index/lrank streams stay NT.
__global__ __launch_bounds__(256) void k_fill_cs(
    const int* __restrict__ node_idx,
    const int* __restrict__ edge_idx,
    const u16* __restrict__ lrankE, const u16* __restrict__ lrankV,
    const u32* __restrict__ baseE,  // rowptr-folded [NCHE][E]
    const u32* __restrict__ baseV,  // rowptr-folded [NCHV][N]
    int* __restrict__ adjE, int* __restrict__ adjV,
    int nnz, int E, int N, int ciE, int ciV)
{
    const int s = blockIdx.x & (NSLICE - 1);
    const int g = blockIdx.x >> 3;
    const int ngroups = gridDim.x >> 3;
    const int eb = (E + NSLICE - 1) / NSLICE;
    const int nb = (N + NSLICE - 1) / NSLICE;
    const int elo = s * eb, ehi = min(E, elo + eb);
    const int nlo = s * nb, nhi = min(N, nlo + nb);

    const int stride = ngroups * 256;
    for (int i = g * 256 + threadIdx.x; i < nnz; i += stride) {
        int n = __builtin_nontemporal_load(node_idx + i);
        int e = __builtin_nontemporal_load(edge_idx + i);
        if (e >= elo && e < ehi) {
            int ce = (int)((unsigned)i / (unsigned)ciE);
            int p = (int)baseE[(size_t)ce * E + e]
                  + (int)__builtin_nontemporal_load(lrankE + i);
            adjE[p] = n;
        }
        if (n >= nlo && n < nhi) {
            int cv = (int)((unsigned)i / (unsigned)ciV);
            int p = (int)baseV[(size_t)cv * N + n]
                  + (int)__builtin_nontemporal_load(lrankV + i);
            adjV[p] = e;
        }
    }
}

// ===========================================================================
// Shared scan infrastructure
// ===========================================================================
__global__ __launch_bounds__(256) void k_chunk_sums(
    const int* __restrict__ cnt, int L, int* __restrict__ partials)
{
    __shared__ int red[256];
    const int tid = threadIdx.x;
    const int base = blockIdx.x * 4096;
    int s = 0;
    for (int j = tid; j < 4096; j += 256) {
        int i = base + j;
        s += (i < L) ? cnt[i] : 0;
    }
    red[tid] = s;
    __syncthreads();
    for (int off = 128; off > 0; off >>= 1) {
        if (tid < off) red[tid] += red[tid + off];
        __syncthreads();
    }
    if (tid == 0) partials[blockIdx.x] = red[0];
}

__global__ void k_scan_partials2(int* __restrict__ pE, int nbE, int* __restrict__ totE,
                                 int* __restrict__ pV, int nbV, int* __restrict__ totV)
{
    if (threadIdx.x != 0) return;
    int* p = (blockIdx.x == 0) ? pE : pV;
    int  nb = (blockIdx.x == 0) ? nbE : nbV;
    int* tot = (blockIdx.x == 0) ? totE : totV;
    int run = 0;
    for (int b = 0; b < nb; ++b) {
        int t = p[b];
        p[b] = run;
        run += t;
    }
    *tot = run;
}

__global__ __launch_bounds__(256) void k_scan_chunks(
    const int* __restrict__ cnt, int L,
    const int* __restrict__ partials,
    int* __restrict__ rowptr, int* __restrict__ cursor)
{
    __shared__ int tsum[256];
    const int tid = threadIdx.x;
    const int tbase = blockIdx.x * 4096 + tid * 16;
    int loc[16];
    int s = 0;
    #pragma unroll
    for (int k = 0; k < 16; ++k) {
        int i = tbase + k;
        loc[k] = (i < L) ? cnt[i] : 0;
        s += loc[k];
    }
    tsum[tid] = s;
    __syncthreads();
    if (tid == 0) {
        int run = partials[blockIdx.x];
        for (int j = 0; j < 256; ++j) {
            int t = tsum[j];
            tsum[j] = run;
            run += t;
        }
    }
    __syncthreads();
    int run = tsum[tid];
    #pragma unroll
    for (int k = 0; k < 16; ++k) {
        int i = tbase + k;
        if (i < L) {
            rowptr[i] = run;
            if (cursor) cursor[i] = run;
        }
        run += loc[k];
    }
}

// ===========================================================================
// bf16 gather stages (tier-0)
// ===========================================================================
__global__ __launch_bounds__(256) void k_gather_edge_bf(
    const u32* __restrict__ vfeat_bf,
    const float* __restrict__ degE,
    const int* __restrict__ rowptrE,
    const int* __restrict__ adjE,
    float* __restrict__ efeat,
    u32* __restrict__ efsc,
    int n_edges)
{
    const int row = (blockIdx.x * blockDim.x + threadIdx.x) >> 6;
    if (row >= n_edges) return;
    const int lane = threadIdx.x & 63;
    const int beg = rowptrE[row];
    const int len = rowptrE[row + 1] - beg;

    const u32* vb = vfeat_bf + lane;
    float2 c0 = {0,0}, c1 = {0,0}, c2 = {0,0}, c3 = {0,0};
    float2 c4 = {0,0}, c5 = {0,0}, c6 = {0,0}, c7 = {0,0};

    int k = 0;
    for (; k + 8 <= len; k += 8) {
        int e0 = adjE[beg + k + 0]; int e1 = adjE[beg + k + 1];
        int e2 = adjE[beg + k + 2]; int e3 = adjE[beg + k + 3];
        int e4 = adjE[beg + k + 4]; int e5 = adjE[beg + k + 5];
        int e6 = adjE[beg + k + 6]; int e7 = adjE[beg + k + 7];
        u32 r0 = vb[(size_t)e0 * 64]; u32 r1 = vb[(size_t)e1 * 64];
        u32 r2 = vb[(size_t)e2 * 64]; u32 r3 = vb[(size_t)e3 * 64];
        u32 r4 = vb[(size_t)e4 * 64]; u32 r5 = vb[(size_t)e5 * 64];
        u32 r6 = vb[(size_t)e6 * 64]; u32 r7 = vb[(size_t)e7 * 64];
        c0.x += bflo(r0); c0.y += bfhi(r0);
        c1.x += bflo(r1); c1.y += bfhi(r1);
        c2.x += bflo(r2); c2.y += bfhi(r2);
        c3.x += bflo(r3); c3.y += bfhi(r3);
        c4.x += bflo(r4); c4.y += bfhi(r4);
        c5.x += bflo(r5); c5.y += bfhi(r5);
        c6.x += bflo(r6); c6.y += bfhi(r6);
        c7.x += bflo(r7); c7.y += bfhi(r7);
    }
    for (; k < len; ++k) {
        u32 r0 = vb[(size_t)adjE[beg + k] * 64];
        c0.x += bflo(r0); c0.y += bfhi(r0);
    }
    float inv = (len > 0) ? 1.0f / (float)len : 0.0f;
    float2 o;
    o.x = (c0.x + c1.x + c2.x + c3.x + c4.x + c5.x + c6.x + c7.x) * inv;
    o.y = (c0.y + c1.y + c2.y + c3.y + c4.y + c5.y + c6.y + c7.y) * inv;
    ((float2*)(efeat + (size_t)row * DD))[lane] = o;
    const float dE = degE[row];
    __builtin_nontemporal_store(packbf2(o.x * dE, o.y * dE),
                                efsc + (size_t)row * 64 + lane);
}

__global__ __launch_bounds__(256) void k_gather_node_vi_bf(
    const u32* __restrict__ efsc,
    const float* __restrict__ degV,
    const float* __restrict__ vfeat0,
    const float* __restrict__ alpha,
    const int* __restrict__ rowptrV,
    const int* __restrict__ adjV,
    float* __restrict__ vi,
    int n_nodes)
{
    const int row = (blockIdx.x * blockDim.x + threadIdx.x) >> 6;
    if (row >= n_nodes) return;
    const int lane = threadIdx.x & 63;
    const int beg = rowptrV[row];
    const int len = rowptrV[row + 1] - beg;

    const u32* eb = efsc + lane;
    float2 c0 = {0,0}, c1 = {0,0}, c2 = {0,0}, c3 = {0,0};
    float2 c4 = {0,0}, c5 = {0,0}, c6 = {0,0}, c7 = {0,0};

    int k = 0;
    for (; k + 8 <= len; k += 8) {
        int e0 = adjV[beg + k + 0]; int e1 = adjV[beg + k + 1];
        int e2 = adjV[beg + k + 2]; int e3 = adjV[beg + k + 3];
        int e4 = adjV[beg + k + 4]; int e5 = adjV[beg + k + 5];
        int e6 = adjV[beg + k + 6]; int e7 = adjV[beg + k + 7];
        u32 r0 = eb[(size_t)e0 * 64]; u32 r1 = eb[(size_t)e1 * 64];
        u32 r2 = eb[(size_t)e2 * 64]; u32 r3 = eb[(size_t)e3 * 64];
        u32 r4 = eb[(size_t)e4 * 64]; u32 r5 = eb[(size_t)e5 * 64];
        u32 r6 = eb[(size_t)e6 * 64]; u32 r7 = eb[(size_t)e7 * 64];
        c0.x += bflo(r0); c0.y += bfhi(r0);
        c1.x += bflo(r1); c1.y += bfhi(r1);
        c2.x += bflo(r2); c2.y += bfhi(r2);
        c3.x += bflo(r3); c3.y += bfhi(r3);
        c4.x += bflo(r4); c4.y += bfhi(r4);
        c5.x += bflo(r5); c5.y += bfhi(r5);
        c6.x += bflo(r6); c6.y += bfhi(r6);
        c7.x += bflo(r7); c7.y += bfhi(r7);
    }
    for (; k < len; ++k) {
        u32 r0 = eb[(size_t)adjV[beg + k] * 64];
        c0.x += bflo(r0); c0.y += bfhi(r0);
    }
    const float a = alpha[0];
    const float s = (1.0f - a) * degV[row];
    const float2 f = ((const float2*)(vfeat0 + (size_t)row * DD))[lane];
    float2 o;
    o.x = s * (c0.x + c1.x + c2.x + c3.x + c4.x + c5.x + c6.x + c7.x) + a * f.x;
    o.y = s * (c0.y + c1.y + c2.y + c3.y + c4.y + c5.y + c6.y + c7.y) + a * f.y;
    ((float2*)(vi + (size_t)row * DD))[lane] = o;
}

// ===========================================================================
// f32 gather stages (fallback tiers)
// ===========================================================================
__global__ __launch_bounds__(256) void k_gather_edge(
    const float* __restrict__ vfeat,
    const int* __restrict__ rowptrE,
    const int* __restrict__ adjE,
    float* __restrict__ efeat,
    int n_edges)
{
    const int row = (blockIdx.x * blockDim.x + threadIdx.x) >> 6;
    if (row >= n_edges) return;
    const int lane = threadIdx.x & 63;
    const int beg = rowptrE[row];
    const int len = rowptrE[row + 1] - beg;

    const float2* vb = (const float2*)vfeat + lane;
    float2 c0 = {0,0}, c1 = {0,0}, c2 = {0,0}, c3 = {0,0};
    int k = 0;
    for (; k + 4 <= len; k += 4) {
        int e0 = adjE[beg + k + 0]; int e1 = adjE[beg + k + 1];
        int e2 = adjE[beg + k + 2]; int e3 = adjE[beg + k + 3];
        float2 r0 = vb[(size_t)e0 * 64]; float2 r1 = vb[(size_t)e1 * 64];
        float2 r2 = vb[(size_t)e2 * 64]; float2 r3 = vb[(size_t)e3 * 64];
        c0.x += r0.x; c0.y += r0.y; c1.x += r1.x; c1.y += r1.y;
        c2.x += r2.x; c2.y += r2.y; c3.x += r3.x; c3.y += r3.y;
    }
    for (; k < len; ++k) {
        float2 r0 = vb[(size_t)adjE[beg + k] * 64];
        c0.x += r0.x; c0.y += r0.y;
    }
    float inv = (len > 0) ? 1.0f / (float)len : 0.0f;
    float2 o;
    o.x = (c0.x + c1.x + c2.x + c3.x) * inv;
    o.y = (c0.y + c1.y + c2.y + c3.y) * inv;
    ((float2*)(efeat + (size_t)row * DD))[lane] = o;
}

__global__ __launch_bounds__(256) void k_gather_node_vi(
    const float* __restrict__ efeat,
    const float* __restrict__ degE,
    const float* __restrict__ degV,
    const float* __restrict__ vfeat0,
    const float* __restrict__ alpha,
    const int* __restrict__ rowptrV,
    const int* __restrict__ adjV,
    float* __restrict__ vi,
    int n_nodes)
{
    const int row = (blockIdx.x * blockDim.x + threadIdx.x) >> 6;
    if (row >= n_nodes) return;
    const int lane = threadIdx.x & 63;
    const int beg = rowptrV[row];
    const int len = rowptrV[row + 1] - beg;

    const float2* eb = (const float2*)efeat + lane;
    float2 c0 = {0,0}, c1 = {0,0}, c2 = {0,0}, c3 = {0,0};
    int k = 0;
    for (; k + 4 <= len; k += 4) {
        int e0 = adjV[beg + k + 0]; int e1 = adjV[beg + k + 1];
        int e2 = adjV[beg + k + 2]; int e3 = adjV[beg + k + 3];
        float w0 = degE[e0], w1 = degE[e1], w2 = degE[e2], w3 = degE[e3];
        float2 r0 = eb[(size_t)e0 * 64]; float2 r1 = eb[(size_t)e1 * 64];
        float2 r2 = eb[(size_t)e2 * 64]; float2 r3 = eb[(size_t)e3 * 64];
        c0.x += w0 * r0.x; c0.y += w0 * r0.y;
        c1.x += w1 * r1.x; c1.y += w1 * r1.y;
        c2.x += w2 * r2.x; c2.y += w2 * r2.y;
        c3.x += w3 * r3.x; c3.y += w3 * r3.y;
    }
    for (; k < len; ++k) {
        int e0 = adjV[beg + k];
        float w0 = degE[e0];
        float2 r0 = eb[(size_t)e0 * 64];
        c0.x += w0 * r0.x; c0.y += w0 * r0.y;
    }
    const float a = alpha[0];
    const float s = (1.0f - a) * degV[row];
    const float2 f = ((const float2*)(vfeat0 + (size_t)row * DD))[lane];
    float2 o;
    o.x = s * (c0.x + c1.x + c2.x + c3.x) + a * f.x;
    o.y = s * (c0.y + c1.y + c2.y + c3.y) + a * f.y;
    ((float2*)(vi + (size_t)row * DD))[lane] = o;
}

// ---------------------------------------------------------------------------
// K-chunked, double-buffered epilogue GEMM, in place on vout (vi -> v).
// ---------------------------------------------------------------------------
__global__ __launch_bounds__(256) void k_gemm_vi(
    float* __restrict__ vout,
    const float* __restrict__ W,
    const float* __restrict__ beta,
    int n_nodes)
{
    __shared__ float Wc[2][128][CK + 4];
    __shared__ float Ac[2][64][CK];

    const int tid = threadIdx.x;
    const float b = beta[0];
    const int nb = blockIdx.x * 64;
    const int tx = tid & 31;
    const int ty = tid >> 5;

    float acc[8][4];
    #pragma unroll
    for (int i = 0; i < 8; ++i)
        #pragma unroll
        for (int j = 0; j < 4; ++j) acc[i][j] = 0.0f;

    auto stage = [&](int chunk, int buf) {
        const int kb = chunk * CK;
        #pragma unroll
        for (int p = 0; p < 4; ++p) {
            int idx = tid + p * 256;
            int row = idx >> 3;
            int l4 = (idx & 7) << 2;
            *(float4*)&Wc[buf][row][l4] = *(const float4*)(W + row * DD + kb + l4);
        }
        #pragma unroll
        for (int p = 0; p < 2; ++p) {
            int idx = tid + p * 256;
            int row = idx >> 3;
            int l4 = (idx & 7) << 2;
            int n = nb + row;
            float4 v = {0, 0, 0, 0};
            if (n < n_nodes) v = *(const float4*)(vout + (size_t)n * DD + kb + l4);
            *(float4*)&Ac[buf][row][l4] = v;
        }
    };

    stage(0, 0);
    __syncthreads();

    const int NCHUNK = DD / CK;
    for (int c = 0; c < NCHUNK; ++c) {
        if (c + 1 < NCHUNK) stage(c + 1, (c + 1) & 1);
        const int buf = c & 1;
        #pragma unroll
        for (int kc = 0; kc < CK / 4; ++kc) {
            const int k4 = kc << 2;
            float4 af[8];
            #pragma unroll
            for (int i = 0; i < 8; ++i) af[i] = *(const float4*)&Ac[buf][ty * 8 + i][k4];
            float4 bf[4];
            #pragma unroll
            for (int j = 0; j < 4; ++j) bf[j] = *(const float4*)&Wc[buf][tx + 32 * j][k4];
            #pragma unroll
            for (int i = 0; i < 8; ++i) {
                #pragma unroll
                for (int j = 0; j < 4; ++j) {
                    acc[i][j] += af[i].x * bf[j].x;
                    acc[i][j] += af[i].y * bf[j].y;
                    acc[i][j] += af[i].z * bf[j].z;
                    acc[i][j] += af[i].w * bf[j].w;
                }
            }
        }
        __syncthreads();
    }

    const float omb = 1.0f - b;
    #pragma unroll
    for (int i = 0; i < 8; ++i) {
        int n = nb + ty * 8 + i;
        if (n < n_nodes) {
            #pragma unroll
            for (int j = 0; j < 4; ++j) {
                int cidx = tx + 32 * j;
                float viv = vout[(size_t)n * DD + cidx];
                vout[(size_t)n * DD + cidx] = omb * viv + b * acc[i][j];
            }
        }
    }
}

// ===========================================================================
// Deep-fallback kernels
// ===========================================================================
__global__ __launch_bounds__(256) void k_hist_rank(
    const int* __restrict__ node_idx, const int* __restrict__ edge_idx,
    int* __restrict__ countE, int* __restrict__ countV,
    int* __restrict__ rankE, int* __restrict__ rankV, int nnz)
{
    int i = blockIdx.x * blockDim.x + threadIdx.x;
    if (i >= nnz) return;
    int e = __builtin_nontemporal_load(edge_idx + i);
    int n = __builtin_nontemporal_load(node_idx + i);
    int re = atomicAdd(&countE[e], 1);
    int rv = atomicAdd(&countV[n], 1);
    __builtin_nontemporal_store(re, rankE + i);
    __builtin_nontemporal_store(rv, rankV + i);
}

__global__ __launch_bounds__(256) void k_fill_sliced_rank(
    const int* __restrict__ node_idx, const int* __restrict__ edge_idx,
    const int* __restrict__ rankE, const int* __restrict__ rankV,
    const int* __restrict__ rowptrE, const int* __restrict__ rowptrV,
    int* __restrict__ adjE, int* __restrict__ adjV,
    int nnz, int E, int N)
{
    const int s = blockIdx.x & (NSLICE - 1);
    const int g = blockIdx.x >> 3;
    const int ngroups = gridDim.x >> 3;
    const int eb = (E + NSLICE - 1) / NSLICE;
    const int nb = (N + NSLICE - 1) / NSLICE;
    const int elo = s * eb, ehi = min(E, elo + eb);
    const int nlo = s * nb, nhi = min(N, nlo + nb);
    const int stride = ngroups * 256;
    for (int i = g * 256 + threadIdx.x; i < nnz; i += stride) {
        int n = __builtin_nontemporal_load(node_idx + i);
        int e = __builtin_nontemporal_load(edge_idx + i);
        if (e >= elo && e < ehi) {
            int p = rowptrE[e] + __builtin_nontemporal_load(rankE + i);
            adjE[p] = n;
        }
        if (n >= nlo && n < nhi) {
            int p = rowptrV[n] + __builtin_nontemporal_load(rankV + i);
            adjV[p] = e;
        }
    }
}

__global__ __launch_bounds__(256) void k_scatter_edge(
    const float* __restrict__ vfeat, const int* __restrict__ node_idx,
    const int* __restrict__ edge_idx, float* __restrict__ esum,
    float* __restrict__ cnt, int nnz)
{
    int t = blockIdx.x * blockDim.x + threadIdx.x;
    int i = t >> 5;
    if (i >= nnz) return;
    int c = (t & 31) << 2;
    int n = node_idx[i];
    int e = edge_idx[i];
    const float4 v = *(const float4*)(vfeat + (size_t)n * DD + c);
    float* dst = esum + (size_t)e * DD + c;
    atomicAdd(dst + 0, v.x); atomicAdd(dst + 1, v.y);
    atomicAdd(dst + 2, v.z); atomicAdd(dst + 3, v.w);
    if ((t & 31) == 0) atomicAdd(cnt + e, 1.0f);
}

__global__ __launch_bounds__(256) void k_normalize_edge(
    float* __restrict__ efeat, const float* __restrict__ cnt, int n_edges)
{
    int t = blockIdx.x * blockDim.x + threadIdx.x;
    int e = t >> 5;
    if (e >= n_edges) return;
    int c = (t & 31) << 2;
    float inv = 1.0f / fmaxf(cnt[e], 1.0f);
    float4* p = (float4*)(efeat + (size_t)e * DD + c);
    float4 v = *p;
    v.x *= inv; v.y *= inv; v.z *= inv; v.w *= inv;
    *p = v;
}

__global__ __launch_bounds__(256) void k_scatter_node_vi(
    const float* __restrict__ efeat_new, const float* __restrict__ degE,
    const int* __restrict__ node_idx, const int* __restrict__ edge_idx,
    float* __restrict__ h, int nnz)
{
    int t = blockIdx.x * blockDim.x + threadIdx.x;
    int i = t >> 5;
    if (i >= nnz) return;
    int c = (t & 31) << 2;
    int n = node_idx[i];
    int e = edge_idx[i];
    float w = degE[e];
    const float4 v = *(const float4*)(efeat_new + (size_t)e * DD + c);
    float* dst = h + (size_t)n * DD + c;
    atomicAdd(dst + 0, w * v.x); atomicAdd(dst + 1, w * v.y);
    atomicAdd(dst + 2, w * v.z); atomicAdd(dst + 3, w * v.w);
}

__global__ __launch_bounds__(256) void k_h_to_vi(
    float* __restrict__ h, const float* __restrict__ degV,
    const float* __restrict__ vfeat0, const float* __restrict__ alpha,
    int n_nodes)
{
    int t = blockIdx.x * blockDim.x + threadIdx.x;
    int n = t >> 5;
    if (n >= n_nodes) return;
    int c = (t & 31) << 2;
    float a = alpha[0];
    float s = (1.0f - a) * degV[n];
    float4* p = (float4*)(h + (size_t)n * DD + c);
    const float4 f = *(const float4*)(vfeat0 + (size_t)n * DD + c);
    float4 v = *p;
    v.x = s * v.x + a * f.x;
    v.y = s * v.y + a * f.y;
    v.z = s * v.z + a * f.z;
    v.w = s * v.w + a * f.w;
    *p = v;
}

// ===========================================================================
extern "C" void kernel_launch(void* const* d_in, const int* in_sizes, int n_in,
                              void* d_out, int out_size, void* d_ws, size_t ws_size,
                              hipStream_t stream)
{
    const float* vfeat  = (const float*)d_in[0];
    const float* degE   = (const float*)d_in[2];
    const float* degV   = (const float*)d_in[3];
    const float* vfeat0 = (const float*)d_in[4];
    const float* W      = (const float*)d_in[5];
    const float* alpha  = (const float*)d_in[6];
    const float* beta   = (const float*)d_in[7];
    const int* node_idx = (const int*)d_in[8];
    const int* edge_idx = (const int*)d_in[9];

    const int E   = in_sizes[2];
    const int N   = in_sizes[3];
    const int NNZ = in_sizes[8];

    float* vout = (float*)d_out;
    float* eout = (float*)d_out + (size_t)N * DD;

    const int nbE = (E + 4095) / 4096;
    const int nbV = (N + 4095) / 4096;
    const int ciE = (NNZ + NCHE - 1) / NCHE;
    const int ciV = (NNZ + NCHV - 1) / NCHV;

    const size_t lrank_w = ((size_t)NNZ + 1) / 2;
    const size_t cs_words =
        (size_t)E + N + (E + 1) + (N + 1) + 128
        + 2 * lrank_w
        + ((size_t)NCHE * E + 1) / 2 + ((size_t)NCHV * N + 1) / 2
        + (size_t)NCHE * E + (size_t)NCHV * N
        + 2 * (size_t)NNZ;
    const size_t need_cs = cs_words * sizeof(int);
    const size_t bf_words = ((size_t)N * 64) + ((size_t)E * 64);
    const size_t need_bf = (cs_words + bf_words) * sizeof(int);
    const size_t need_rank = ((size_t)2 * E + 2 * N + 4 * (size_t)NNZ + 130) * sizeof(int);

    const bool cs_shape_ok = (E <= 20000) && (N <= 100000) && !(E & 1) && !(N & 1)
                             && ciE <= 65535 && ciV <= 65535 && !(DD & 1);

    if (cs_shape_ok && ws_size >= need_cs) {
        int* countE  = (int*)d_ws;
        int* countV  = countE + E;
        int* rowptrE = countV + N;
        int* rowptrV = rowptrE + E + 1;
        int* partE   = rowptrV + N + 1;
        int* partV   = partE + 64;
        u16* lrankE = (u16*)(partV + 64);
        u16* lrankV = lrankE + 2 * lrank_w;
        u16* histE  = lrankV + 2 * lrank_w;
        u16* histV  = histE + 2 * (((size_t)NCHE * E + 1) / 2);
        u32* baseE  = (u32*)(histV + 2 * (((size_t)NCHV * N + 1) / 2));
        u32* baseV  = baseE + (size_t)NCHE * E;
        int* adjE = (int*)(baseV + (size_t)NCHV * N);
        int* adjV = adjE + NNZ;
        u32* vfeat_bf = (u32*)(adjV + NNZ);
        u32* efsc_bf  = vfeat_bf + (size_t)N * 64;

        const bool bf_ok = ws_size >= need_bf;

        if (bf_ok) {
            int npairs = N * 64;
            k_to_bf16<<<(npairs + 255) / 256, 256, 0, stream>>>(vfeat, vfeat_bf, npairs);
        }
        k_cnt_rank_E<<<NCHE, 1024, 0, stream>>>(edge_idx, lrankE, histE, NNZ, ciE, E);
        k_cnt_rank_V<<<dim3(NCHV, 2), 1024, 0, stream>>>(node_idx, lrankV, histV, NNZ, ciV, N);
        k_sum_prefix<<<(E + 255) / 256, 256, 0, stream>>>(histE, baseE, countE, E, NCHE);
        k_sum_prefix<<<(N + 255) / 256, 256, 0, stream>>>(histV, baseV, countV, N, NCHV);
        k_chunk_sums<<<nbE, 256, 0, stream>>>(countE, E, partE);
        k_chunk_sums<<<nbV, 256, 0, stream>>>(countV, N, partV);
        k_scan_partials2<<<2, 64, 0, stream>>>(partE, nbE, rowptrE + E,
                                               partV, nbV, rowptrV + N);
        k_scan_chunks<<<nbE, 256, 0, stream>>>(countE, E, partE, rowptrE, nullptr);
        k_scan_chunks<<<nbV, 256, 0, stream>>>(countV, N, partV, rowptrV, nullptr);
        // fold rowptr into base tables (one random load per side in fill)
        k_add_rowptr<<<dim3((E + 255) / 256, NCHE), 256, 0, stream>>>(baseE, rowptrE, E);
        k_add_rowptr<<<dim3((N + 255) / 256, NCHV), 256, 0, stream>>>(baseV, rowptrV, N);

        k_fill_cs<<<2048, 256, 0, stream>>>(node_idx, edge_idx, lrankE, lrankV,
                                            baseE, baseV,
                                            adjE, adjV, NNZ, E, N, ciE, ciV);

        if (bf_ok) {
            k_gather_edge_bf<<<((size_t)E * 64 + 255) / 256, 256, 0, stream>>>(
                vfeat_bf, degE, rowptrE, adjE, eout, efsc_bf, E);
            k_gather_node_vi_bf<<<((size_t)N * 64 + 255) / 256, 256, 0, stream>>>(
                efsc_bf, degV, vfeat0, alpha, rowptrV, adjV, vout, N);
        } else {
            k_gather_edge<<<((size_t)E * 64 + 255) / 256, 256, 0, stream>>>(
                vfeat, rowptrE, adjE, eout, E);
            k_gather_node_vi<<<((size_t)N * 64 + 255) / 256, 256, 0, stream>>>(
                eout, degE, degV, vfeat0, alpha, rowptrV, adjV, vout, N);
        }
        k_gemm_vi<<<(N + 63) / 64, 256, 0, stream>>>(vout, W, beta, N);
    } else if (ws_size >= need_rank) {
        int* countE  = (int*)d_ws;
        int* countV  = countE + E;
        int* rowptrE = countV + N;
        int* rowptrV = rowptrE + E + 1;
        int* partE   = rowptrV + N + 1;
        int* partV   = partE + 64;
        int* rankE   = partV + 64;
        int* rankV   = rankE + NNZ;
        int* adjE    = rankV + NNZ;
        int* adjV    = adjE + NNZ;

        hipMemsetAsync(countE, 0, (size_t)(E + N) * sizeof(int), stream);
        k_hist_rank<<<(NNZ + 255) / 256, 256, 0, stream>>>(
            node_idx, edge_idx, countE, countV, rankE, rankV, NNZ);
        k_chunk_sums<<<nbE, 256, 0, stream>>>(countE, E, partE);
        k_chunk_sums<<<nbV, 256, 0, stream>>>(countV, N, partV);
        k_scan_partials2<<<2, 64, 0, stream>>>(partE, nbE, rowptrE + E,
                                               partV, nbV, rowptrV + N);
        k_scan_chunks<<<nbE, 256, 0, stream>>>(countE, E, partE, rowptrE, nullptr);
        k_scan_chunks<<<nbV, 256, 0, stream>>>(countV, N, partV, rowptrV, nullptr);
        k_fill_sliced_rank<<<2048, 256, 0, stream>>>(
            node_idx, edge_idx, rankE, rankV, rowptrE, rowptrV,
            adjE, adjV, NNZ, E, N);
        k_gather_edge<<<((size_t)E * 64 + 255) / 256, 256, 0, stream>>>(
            vfeat, rowptrE, adjE, eout, E);
        k_gather_node_vi<<<((size_t)N * 64 + 255) / 256, 256, 0, stream>>>(
            eout, degE, degV, vfeat0, alpha, rowptrV, adjV, vout, N);
        k_gemm_vi<<<(N + 63) / 64, 256, 0, stream>>>(vout, W, beta, N);
    } else {
        float* cnt = (float*)d_ws;
        hipMemsetAsync(d_out, 0, (size_t)out_size * sizeof(float), stream);
        hipMemsetAsync(cnt, 0, (size_t)E * sizeof(float), stream);
        {
            long long threads = (long long)NNZ * 32;
            int blocks = (int)((threads + 255) / 256);
            k_scatter_edge<<<blocks, 256, 0, stream>>>(vfeat, node_idx, edge_idx,
                                                       eout, cnt, NNZ);
        }
        {
            int blocks = (E * 32 + 255) / 256;
            k_normalize_edge<<<blocks, 256, 0, stream>>>(eout, cnt, E);
        }
        {
            long long threads = (long long)NNZ * 32;
            int blocks = (int)((threads + 255) / 256);
            k_scatter_node_vi<<<blocks, 256, 0, stream>>>(eout, degE, node_idx, edge_idx,
                                                          vout, NNZ);
        }
        k_h_to_vi<<<((size_t)N * 32 + 255) / 256, 256, 0, stream>>>(
            vout, degV, vfeat0, alpha, N);
        k_gemm_vi<<<(N + 63) / 64, 256, 0, stream>>>(vout, W, beta, N);
    }
}